// Round 3
// baseline (155.354 us; speedup 1.0000x reference)
//
#include <hip/hip_runtime.h>
#include <hip/hip_bf16.h>

// out = softmax((X Wq + bq)(X Wk + bk)^T / 8) (X Wv + bv) Wo + bo
// All prune/straight-through ops in the reference are value-wise identity.
//
// Pipeline (all bf16 MFMA 16x16x32, fp32 accum):
//   k_cvt : hs fp32 -> bf16 A [4736][768]   (rows 4616..4735 zero pad)
//   k_wt  : W fp32 [k][n] -> bf16 Wt [n][k]  (x4 weights)
//   k_pad : zero kh pad rows [577,640) and vt pad cols [576,640)
//   k_gemm: 128x128 tile, double-buffered global_load_lds staging (counted vmcnt),
//           mode 0 (z=0,1,2): QKV -> qh [B,h,S,64], kh [B,h,640,64], vt [B,h,64,640]
//           mode 3: ctx @ Wo + bo -> d_out fp32
//   k_attn: flash attention, K/V double-buffered gload_lds, XCD-pinned grid (bh%8)

#define B_ 8
#define S_ 577
#define H_ 768
#define NH_ 12
#define HD_ 64
#define M_ (B_*S_)     /* 4616 */
#define MPAD 4736      /* 37*128 */
#define BH_ (B_*NH_)   /* 96 */
#define SKPAD 640      /* padded key count */

typedef __attribute__((ext_vector_type(8))) short short8;
typedef __attribute__((ext_vector_type(4))) float f32x4;

__device__ inline unsigned short f2bf(float f){
    unsigned int u = __float_as_uint(f);
    u = u + 0x7fffu + ((u>>16)&1u);     // round-to-nearest-even
    return (unsigned short)(u>>16);
}

__device__ inline void gload_lds16(const short* g, short* l){
    __builtin_amdgcn_global_load_lds((const __attribute__((address_space(1))) void*)g,
                                     (__attribute__((address_space(3))) void*)l, 16, 0, 0);
}

// convert hs -> bf16, zero the pad rows [4616..4736)
__global__ __launch_bounds__(256) void k_cvt(const float* __restrict__ x, short* __restrict__ y){
    int i = blockIdx.x*256 + threadIdx.x;
    if(blockIdx.x >= 1731){                // pad region: 45 blocks
        *(short8*)(y + (size_t)i*8) = (short8){};
        return;
    }
    const float4* p = (const float4*)(x + (size_t)i*8);
    float4 a = p[0], b = p[1];
    short8 v;
    v[0]=(short)f2bf(a.x); v[1]=(short)f2bf(a.y); v[2]=(short)f2bf(a.z); v[3]=(short)f2bf(a.w);
    v[4]=(short)f2bf(b.x); v[5]=(short)f2bf(b.y); v[6]=(short)f2bf(b.z); v[7]=(short)f2bf(b.w);
    *(short8*)(y + (size_t)i*8) = v;
}

// transpose + convert: T[n][k] = bf16(W[k][n])
__global__ __launch_bounds__(256) void k_wt(const float* __restrict__ Wq, const float* __restrict__ Wk,
                                            const float* __restrict__ Wv, const float* __restrict__ Wo,
                                            short* __restrict__ Tq, short* __restrict__ Tk,
                                            short* __restrict__ Tv, short* __restrict__ To){
    const float* W = blockIdx.z==0?Wq: blockIdx.z==1?Wk: blockIdx.z==2?Wv:Wo;
    short*       T = blockIdx.z==0?Tq: blockIdx.z==1?Tk: blockIdx.z==2?Tv:To;
    __shared__ float lds[64][65];
    int t = threadIdx.x;
    int k0 = blockIdx.x*64, n0 = blockIdx.y*64;
    for(int i=0;i<4;i++){
        int row = i*16 + (t>>4);
        int col = (t&15)*4;
        float4 v = *(const float4*)&W[(k0+row)*768 + n0 + col];
        lds[row][col]=v.x; lds[row][col+1]=v.y; lds[row][col+2]=v.z; lds[row][col+3]=v.w;
    }
    __syncthreads();
    for(int i=0;i<4;i++){
        int n = i*16 + (t>>4);
        int k4 = (t&15)*4;
        for(int j=0;j<4;j++)
            T[(n0+n)*768 + k0 + k4 + j] = (short)f2bf(lds[k4+j][n]);
    }
}

// zero kh rows [577,640) (full 64-wide) and vt cols [576,640) (col 576 rewritten by gemm)
__global__ __launch_bounds__(256) void k_pad(short* __restrict__ kh, short* __restrict__ vt){
    int tid = blockIdx.x*256 + threadIdx.x;
    short8 z = {};
    if(tid < 48384){                       // 96*63 rows * 8 chunks
        int row_id = tid>>3, ch = tid&7;
        int bh = row_id/63, r = row_id - bh*63;
        *(short8*)&kh[((size_t)bh*SKPAD + 577 + r)*64 + ch*8] = z;
    } else if(tid < 97536){                // 96*64 rows * 8 chunks
        int j = tid - 48384;
        int row_id = j>>3, ch = j&7;
        int bh = row_id>>6, d = row_id&63;
        *(short8*)&vt[((size_t)bh*64 + d)*SKPAD + 576 + ch*8] = z;
    }
}

// 128x128 tile GEMM, double-buffered: out[m][n] = sum_k A[m][k]*T[n][k] + bias[n]
__global__ __launch_bounds__(256) void k_gemm(
    const short* __restrict__ A,
    const short* __restrict__ T0, const short* __restrict__ T1, const short* __restrict__ T2,
    const float* __restrict__ b0, const float* __restrict__ b1, const float* __restrict__ b2,
    short* __restrict__ oq, short* __restrict__ ok, short* __restrict__ ovt,
    float* __restrict__ of, int mode)
{
    __shared__ short lA[2][128*64], lB[2][128*64];
    const int t = threadIdx.x;
    const int m0 = blockIdx.x*128, n0 = blockIdx.y*128;
    const int z = blockIdx.z;
    const short* T    = (mode==3)? T0 : (z==0?T0: z==1?T1:T2);
    const float* bias = (mode==3)? b0 : (z==0?b0: z==1?b1:b2);

    const int w = t>>6, lane = t&63, g = lane>>4, c = lane&15;
    const int wm = w>>1, wn = w&1;

    // staging: lane l -> row (l>>3), dest 16B-slot (l&7); source chunk (l&7)^(row&7)
    // so LDS[row][slot] = G[row][slot ^ (row&7)]  (XOR-swizzled, conflict-free reads)
    const int lrow = lane>>3;
    const int lcol = ((lane&7) ^ lrow) * 8;
    const short* pa = A + (size_t)(m0 + w*32 + lrow)*768 + lcol;
    const short* pb = T + (size_t)(n0 + w*32 + lrow)*768 + lcol;

    f32x4 acc[4][4] = {};

    // prologue: stage K-step 0 into buffer 0
    #pragma unroll
    for(int i=0;i<4;i++){
        gload_lds16(pa + (size_t)i*8*768, &lA[0][(w*32+i*8)*64]);
        gload_lds16(pb + (size_t)i*8*768, &lB[0][(w*32+i*8)*64]);
    }
    int bb = 0;
    for(int kk=0; kk<12; kk++){
        if(kk<11){
            #pragma unroll
            for(int i=0;i<4;i++){
                gload_lds16(pa + (size_t)i*8*768 + (kk+1)*64, &lA[bb^1][(w*32+i*8)*64]);
                gload_lds16(pb + (size_t)i*8*768 + (kk+1)*64, &lB[bb^1][(w*32+i*8)*64]);
            }
            asm volatile("s_waitcnt vmcnt(8)" ::: "memory");
        } else {
            asm volatile("s_waitcnt vmcnt(0)" ::: "memory");
        }
        __builtin_amdgcn_s_barrier();
        asm volatile("" ::: "memory");

        const short* LA = lA[bb]; const short* LB = lB[bb];
        short8 af[4][2], bfv[4][2];
        #pragma unroll
        for(int mi=0; mi<4; mi++){
            int row = wm*64 + mi*16 + c;
            int rx = (row&7)<<3;
            af[mi][0] = *(const short8*)&LA[row*64 + ((g*8) ^ rx)];
            af[mi][1] = *(const short8*)&LA[row*64 + ((32 + g*8) ^ rx)];
        }
        #pragma unroll
        for(int ni=0; ni<4; ni++){
            int row = wn*64 + ni*16 + c;
            int rx = (row&7)<<3;
            bfv[ni][0] = *(const short8*)&LB[row*64 + ((g*8) ^ rx)];
            bfv[ni][1] = *(const short8*)&LB[row*64 + ((32 + g*8) ^ rx)];
        }
        #pragma unroll
        for(int mi=0; mi<4; mi++)
            #pragma unroll
            for(int ni=0; ni<4; ni++){
                acc[mi][ni] = __builtin_amdgcn_mfma_f32_16x16x32_bf16(af[mi][0], bfv[ni][0], acc[mi][ni], 0,0,0);
                acc[mi][ni] = __builtin_amdgcn_mfma_f32_16x16x32_bf16(af[mi][1], bfv[ni][1], acc[mi][ni], 0,0,0);
            }
        asm volatile("s_waitcnt lgkmcnt(0)" ::: "memory");
        __builtin_amdgcn_s_barrier();
        asm volatile("" ::: "memory");
        bb ^= 1;
    }

    #pragma unroll
    for(int mi=0; mi<4; mi++) for(int ni=0; ni<4; ni++){
        #pragma unroll
        for(int r=0; r<4; r++){
            int m = m0 + wm*64 + mi*16 + g*4 + r;   // C/D: row=(lane>>4)*4+reg
            int n = n0 + wn*64 + ni*16 + c;         // C/D: col=lane&15
            if(m >= M_) continue;
            float val = acc[mi][ni][r] + bias[n];
            if(mode==3){
                of[(size_t)m*768 + n] = val;
            } else {
                int s = m % S_, b = m / S_;
                int h = n >> 6, d = n & 63;
                if(z==2)      ovt[(((size_t)b*NH_+h)*HD_ + d)*SKPAD + s] = (short)f2bf(val);
                else if(z==1) ok [(((size_t)b*NH_+h)*SKPAD + s)*HD_ + d] = (short)f2bf(val);
                else          oq [(((size_t)b*NH_+h)*S_ + s)*HD_ + d] = (short)f2bf(val);
            }
        }
    }
}

// flash attention: grid (bh, qtile) -> bh%8 pins same-head blocks to one XCD's L2.
// K/V double-buffered via global_load_lds + counted vmcnt; softmax in exp2 domain.
__global__ __launch_bounds__(256) void k_attn(
    const short* __restrict__ qh, const short* __restrict__ kh, const short* __restrict__ vt,
    short* __restrict__ ctx)
{
    __shared__ short lK[2][64*64], lV[2][64*64], lP[4*16*64];
    const int t = threadIdx.x;
    const int w = t>>6, lane = t&63, g = lane>>4, c = lane&15;
    const int bh = blockIdx.x, b = bh/NH_, h = bh%NH_;
    const int q0 = blockIdx.y*64;

    // per-wave Q staging into own lP region (guarded), then frags to regs
    #pragma unroll
    for(int i=0;i<2;i++){
        int row = i*8 + (lane>>3);
        int e8 = (lane&7)*8;
        int s = q0 + w*16 + row;
        short8 v = {};
        if(s < S_) v = *(const short8*)&qh[((size_t)bh*S_ + s)*HD_ + e8];
        *(short8*)&lP[w*1024 + row*64 + (e8 ^ ((row&7)<<3))] = v;
    }
    short8 qf[2];
    #pragma unroll
    for(int ks=0; ks<2; ks++)
        qf[ks] = *(const short8*)&lP[w*1024 + c*64 + ((ks*32+g*8) ^ ((c&7)<<3))];

    const int srow = lane>>3;
    const int sw8 = ((lane&7) ^ srow)*8;
    const short* pk0 = kh + ((size_t)bh*SKPAD + w*16 + srow)*64 + sw8;
    const short* pv0 = vt + ((size_t)bh*64 + w*16 + srow)*SKPAD + sw8;

    // prologue: stage tile 0 into buffer 0
    #pragma unroll
    for(int i=0;i<2;i++){
        gload_lds16(pk0 + i*8*64,    &lK[0][(w*16+i*8)*64]);
        gload_lds16(pv0 + i*8*SKPAD, &lV[0][(w*16+i*8)*64]);
    }

    float m_run[4], l_run[4];
    f32x4 O[4] = {};
    #pragma unroll
    for(int r=0;r<4;r++){ m_run[r] = -3e38f; l_run[r] = 0.f; }

    int bb = 0;
    for(int kt=0; kt<10; kt++){
        if(kt<9){
            const short* pk = pk0 + (kt+1)*4096;   // 64 rows * 64
            const short* pv = pv0 + (kt+1)*64;     // 64 cols
            #pragma unroll
            for(int i=0;i<2;i++){
                gload_lds16(pk + i*8*64,    &lK[bb^1][(w*16+i*8)*64]);
                gload_lds16(pv + i*8*SKPAD, &lV[bb^1][(w*16+i*8)*64]);
            }
            asm volatile("s_waitcnt vmcnt(4)" ::: "memory");
        } else {
            asm volatile("s_waitcnt vmcnt(0)" ::: "memory");
        }
        __builtin_amdgcn_s_barrier();
        asm volatile("" ::: "memory");

        const short* LK = lK[bb]; const short* LV = lV[bb];

        // S = Q K^T (per wave: 16 q-rows x 64 keys), scaled into log2 domain
        float sv[4][4];
        #pragma unroll
        for(int nt=0; nt<4; nt++){
            f32x4 sa = {};
            int row = nt*16 + c;
            int rx = (row&7)<<3;
            #pragma unroll
            for(int ks=0; ks<2; ks++){
                short8 kf = *(const short8*)&LK[row*64 + ((ks*32+g*8) ^ rx)];
                sa = __builtin_amdgcn_mfma_f32_16x16x32_bf16(qf[ks], kf, sa, 0,0,0);
            }
            #pragma unroll
            for(int r=0;r<4;r++) sv[nt][r] = sa[r]*0.18033688011f;  // /8 * log2(e)
        }
        if(kt==9){
            #pragma unroll
            for(int nt=0; nt<4; nt++){
                int key = 576 + nt*16 + c;
                if(key >= S_){
                    #pragma unroll
                    for(int r=0;r<4;r++) sv[nt][r] = -3e38f;
                }
            }
        }
        // online softmax (exp2 domain; rows live across 16 c-lanes)
        float fac[4], ts[4];
        #pragma unroll
        for(int r=0;r<4;r++){
            float mx = fmaxf(fmaxf(sv[0][r],sv[1][r]),fmaxf(sv[2][r],sv[3][r]));
            for(int off=1; off<16; off<<=1) mx = fmaxf(mx, __shfl_xor(mx, off));
            float nm = fmaxf(m_run[r], mx);
            fac[r] = __builtin_amdgcn_exp2f(m_run[r] - nm);
            m_run[r] = nm;
            ts[r] = 0.f;
        }
        #pragma unroll
        for(int nt=0; nt<4; nt++){
            #pragma unroll
            for(int r=0;r<4;r++){
                float p = __builtin_amdgcn_exp2f(sv[nt][r] - m_run[r]);
                ts[r] += p;
                int prow = g*4 + r;
                lP[w*1024 + prow*64 + ((nt*16 + c) ^ ((prow&7)<<3))] = (short)f2bf(p);
            }
        }
        #pragma unroll
        for(int r=0;r<4;r++){
            for(int off=1; off<16; off<<=1) ts[r] += __shfl_xor(ts[r], off);
            l_run[r] = l_run[r]*fac[r] + ts[r];
        }
        #pragma unroll
        for(int nt=0;nt<4;nt++)
            #pragma unroll
            for(int r=0;r<4;r++) O[nt][r] *= fac[r];

        // O += P V  (P from own-wave LDS region; V^T tile rows = d)
        short8 pf[2];
        #pragma unroll
        for(int ks=0; ks<2; ks++)
            pf[ks] = *(const short8*)&lP[w*1024 + c*64 + ((ks*32+g*8) ^ ((c&7)<<3))];
        #pragma unroll
        for(int nt=0; nt<4; nt++){
            int vrow = nt*16 + c;
            int rx = (vrow&7)<<3;
            #pragma unroll
            for(int ks=0; ks<2; ks++){
                short8 vf = *(const short8*)&LV[vrow*64 + ((ks*32+g*8) ^ rx)];
                O[nt] = __builtin_amdgcn_mfma_f32_16x16x32_bf16(pf[ks], vf, O[nt], 0,0,0);
            }
        }
        asm volatile("s_waitcnt lgkmcnt(0)" ::: "memory");
        __builtin_amdgcn_s_barrier();
        asm volatile("" ::: "memory");
        bb ^= 1;
    }

    #pragma unroll
    for(int nt=0; nt<4; nt++){
        #pragma unroll
        for(int r=0;r<4;r++){
            int s = q0 + w*16 + g*4 + r;
            if(s < S_){
                float val = O[nt][r] / l_run[r];
                ctx[((size_t)b*S_ + s)*H_ + h*HD_ + nt*16 + c] = (short)f2bf(val);
            }
        }
    }
}

extern "C" void kernel_launch(void* const* d_in, const int* in_sizes, int n_in,
                              void* d_out, int out_size, void* d_ws, size_t ws_size,
                              hipStream_t stream)
{
    const float* hs = (const float*)d_in[0];
    const float* Wq = (const float*)d_in[1];
    const float* bq = (const float*)d_in[2];
    const float* Wk = (const float*)d_in[3];
    const float* bk = (const float*)d_in[4];
    const float* Wv = (const float*)d_in[5];
    const float* bv = (const float*)d_in[6];
    const float* Wo = (const float*)d_in[7];
    const float* bo = (const float*)d_in[8];
    float* out = (float*)d_out;

    char* ws = (char*)d_ws;
    // abf/ctx: 4736*768*2 = 7,274,496
    // Wt x4:   768*768*2  = 1,179,648 each (contiguous)
    // qh: 96*577*64*2 = 7,090,176 ; kh: 96*640*64*2 = 7,864,320 ; vt: 96*64*640*2 = 7,864,320
    short* abf = (short*)(ws);
    short* ctx = abf;                               // reuse after QKV GEMM
    short* wqt = (short*)(ws + 7274496);
    short* wkt = (short*)(ws + 7274496 + 1179648);
    short* wvt = (short*)(ws + 7274496 + 2*1179648);
    short* wot = (short*)(ws + 7274496 + 3*1179648);
    short* qh  = (short*)(ws + 11993088);
    short* kh  = (short*)(ws + 19083264);
    short* vt  = (short*)(ws + 26947584);
    // total: 34,811,904 B

    k_cvt<<<1776, 256, 0, stream>>>(hs, abf);
    k_wt<<<dim3(12,12,4), 256, 0, stream>>>(Wq,Wk,Wv,Wo, wqt,wkt,wvt,wot);
    k_pad<<<381, 256, 0, stream>>>(kh, vt);
    k_gemm<<<dim3(37,6,3), 256, 0, stream>>>(abf, wqt,wkt,wvt, bq,bk,bv, qh,kh,vt, nullptr, 0);
    k_attn<<<dim3(96,10), 256, 0, stream>>>(qh, kh, vt, ctx);
    k_gemm<<<dim3(37,6,1), 256, 0, stream>>>(ctx, wot,nullptr,nullptr, bo,nullptr,nullptr,
                                             nullptr,nullptr,nullptr, out, 3);
}

// Round 4
// 153.199 us; speedup vs baseline: 1.0141x; 1.0141x over previous
//
#include <hip/hip_runtime.h>
#include <hip/hip_bf16.h>

// out = softmax((X Wq + bq)(X Wk + bk)^T / 8) (X Wv + bv) Wo + bo
// All prune/straight-through ops in the reference are value-wise identity.
//
// Pipeline (all bf16 MFMA 16x16x32, fp32 accum):
//   k_cvt : hs fp32 -> bf16 A [4736][768]   (rows 4616..4735 zero pad)
//   k_wt  : W fp32 [k][n] -> bf16 Wt [n][k]  (x4, contiguous -> fused [2304][768])
//   k_pad : zero kh pad rows [577,640) and vt pad cols [576,640)
//   k_gemm: fused QKV GEMM (N=2304), 128x128 tile, single-buffer gload_lds,
//           XCD-chunked block swizzle; mode 3 = ctx @ Wo + bo -> d_out fp32
//   k_attn: flash attention, K/V double-buffered gload_lds (counted vmcnt),
//           XCD-pinned grid (bh%8), exp2-domain softmax, MFMA row-sum

#define B_ 8
#define S_ 577
#define H_ 768
#define NH_ 12
#define HD_ 64
#define M_ (B_*S_)     /* 4616 */
#define MPAD 4736      /* 37*128 */
#define BH_ (B_*NH_)   /* 96 */
#define SKPAD 640      /* padded key count */

typedef __attribute__((ext_vector_type(8))) short short8;
typedef __attribute__((ext_vector_type(4))) float f32x4;

__device__ inline unsigned short f2bf(float f){
    unsigned int u = __float_as_uint(f);
    u = u + 0x7fffu + ((u>>16)&1u);     // round-to-nearest-even
    return (unsigned short)(u>>16);
}

__device__ inline void gload_lds16(const short* g, short* l){
    __builtin_amdgcn_global_load_lds((const __attribute__((address_space(1))) void*)g,
                                     (__attribute__((address_space(3))) void*)l, 16, 0, 0);
}

// convert hs -> bf16, zero the pad rows [4616..4736)
__global__ __launch_bounds__(256) void k_cvt(const float* __restrict__ x, short* __restrict__ y){
    int i = blockIdx.x*256 + threadIdx.x;
    if(blockIdx.x >= 1731){                // pad region: 45 blocks
        *(short8*)(y + (size_t)i*8) = (short8){};
        return;
    }
    const float4* p = (const float4*)(x + (size_t)i*8);
    float4 a = p[0], b = p[1];
    short8 v;
    v[0]=(short)f2bf(a.x); v[1]=(short)f2bf(a.y); v[2]=(short)f2bf(a.z); v[3]=(short)f2bf(a.w);
    v[4]=(short)f2bf(b.x); v[5]=(short)f2bf(b.y); v[6]=(short)f2bf(b.z); v[7]=(short)f2bf(b.w);
    *(short8*)(y + (size_t)i*8) = v;
}

// transpose + convert: T[n][k] = bf16(W[k][n])
__global__ __launch_bounds__(256) void k_wt(const float* __restrict__ Wq, const float* __restrict__ Wk,
                                            const float* __restrict__ Wv, const float* __restrict__ Wo,
                                            short* __restrict__ Tq, short* __restrict__ Tk,
                                            short* __restrict__ Tv, short* __restrict__ To){
    const float* W = blockIdx.z==0?Wq: blockIdx.z==1?Wk: blockIdx.z==2?Wv:Wo;
    short*       T = blockIdx.z==0?Tq: blockIdx.z==1?Tk: blockIdx.z==2?Tv:To;
    __shared__ float lds[64][65];
    int t = threadIdx.x;
    int k0 = blockIdx.x*64, n0 = blockIdx.y*64;
    for(int i=0;i<4;i++){
        int row = i*16 + (t>>4);
        int col = (t&15)*4;
        float4 v = *(const float4*)&W[(k0+row)*768 + n0 + col];
        lds[row][col]=v.x; lds[row][col+1]=v.y; lds[row][col+2]=v.z; lds[row][col+3]=v.w;
    }
    __syncthreads();
    for(int i=0;i<4;i++){
        int n = i*16 + (t>>4);
        int k4 = (t&15)*4;
        for(int j=0;j<4;j++)
            T[(n0+n)*768 + k0 + k4 + j] = (short)f2bf(lds[k4+j][n]);
    }
}

// zero kh pad rows [577,640) and vt pad cols [576,640)
__global__ __launch_bounds__(256) void k_pad(short* __restrict__ kh, short* __restrict__ vt){
    int tid = blockIdx.x*256 + threadIdx.x;
    short8 z = {};
    if(tid < 48384){                       // 96*63 rows * 8 chunks
        int row_id = tid>>3, ch = tid&7;
        int bh = row_id/63, r = row_id - bh*63;
        *(short8*)&kh[((size_t)bh*SKPAD + 577 + r)*64 + ch*8] = z;
    } else if(tid < 97536){                // 96*64 rows * 8 chunks
        int j = tid - 48384;
        int row_id = j>>3, ch = j&7;
        int bh = row_id>>6, d = row_id&63;
        *(short8*)&vt[((size_t)bh*64 + d)*SKPAD + 576 + ch*8] = z;
    }
}

// 128x128 tile GEMM, single-buffer m97 structure, XCD-chunked swizzle.
// mode 0: A[4736][768] @ Tqkv[2304][768]^T -> q/k/v (routed by n-segment)
// mode 3: A=ctx @ To[768][768]^T + bo -> of fp32
__global__ __launch_bounds__(256) void k_gemm(
    const short* __restrict__ A, const short* __restrict__ T,
    const float* __restrict__ b0, const float* __restrict__ b1, const float* __restrict__ b2,
    short* __restrict__ oq, short* __restrict__ ok, short* __restrict__ ovt,
    float* __restrict__ of, int mode, int NT)
{
    __shared__ short lA[128*64], lB[128*64];
    const int t = threadIdx.x;

    // bijective XCD-chunked swizzle (m204): contiguous m-major ranges per XCD
    const int nwg = gridDim.x;
    const int q8 = nwg>>3, r8 = nwg&7;
    const int xcd = blockIdx.x&7, cidx = blockIdx.x>>3;
    const int wg = (xcd<r8 ? xcd*(q8+1) : r8*(q8+1) + (xcd-r8)*q8) + cidx;
    const int mt = wg/NT, ntile = wg - mt*NT;
    const int m0 = mt*128, n0 = ntile*128;

    const int seg = (mode==3)? 0 : n0/768;           // block-uniform
    const float* bias = (mode==3)? b0 : (seg==0?b0: seg==1?b1:b2);

    const int w = t>>6, lane = t&63, g = lane>>4, c = lane&15;
    const int wm = w>>1, wn = w&1;

    // staging: lane l -> row (l>>3), dest 16B-slot (l&7); source chunk (l&7)^(row&7)
    // so LDS[row][slot] = G[row][slot ^ (row&7)]  (XOR-swizzled, conflict-free reads)
    const int lrow = lane>>3;
    const int lcol = ((lane&7) ^ lrow) * 8;
    const short* pa = A + (size_t)(m0 + w*32 + lrow)*768 + lcol;
    const short* pb = T + (size_t)(n0 + w*32 + lrow)*768 + lcol;

    f32x4 acc[4][4] = {};

    for(int kk=0; kk<12; kk++){
        #pragma unroll
        for(int i=0;i<4;i++){
            gload_lds16(pa + (size_t)i*8*768 + kk*64, &lA[(w*32+i*8)*64]);
            gload_lds16(pb + (size_t)i*8*768 + kk*64, &lB[(w*32+i*8)*64]);
        }
        __syncthreads();

        short8 af[4][2], bfv[4][2];
        #pragma unroll
        for(int mi=0; mi<4; mi++){
            int row = wm*64 + mi*16 + c;
            int rx = (row&7)<<3;
            af[mi][0] = *(const short8*)&lA[row*64 + ((g*8) ^ rx)];
            af[mi][1] = *(const short8*)&lA[row*64 + ((32 + g*8) ^ rx)];
        }
        #pragma unroll
        for(int ni=0; ni<4; ni++){
            int row = wn*64 + ni*16 + c;
            int rx = (row&7)<<3;
            bfv[ni][0] = *(const short8*)&lB[row*64 + ((g*8) ^ rx)];
            bfv[ni][1] = *(const short8*)&lB[row*64 + ((32 + g*8) ^ rx)];
        }
        #pragma unroll
        for(int mi=0; mi<4; mi++)
            #pragma unroll
            for(int ni=0; ni<4; ni++){
                acc[mi][ni] = __builtin_amdgcn_mfma_f32_16x16x32_bf16(af[mi][0], bfv[ni][0], acc[mi][ni], 0,0,0);
                acc[mi][ni] = __builtin_amdgcn_mfma_f32_16x16x32_bf16(af[mi][1], bfv[ni][1], acc[mi][ni], 0,0,0);
            }
        __syncthreads();
    }

    #pragma unroll
    for(int mi=0; mi<4; mi++) for(int ni=0; ni<4; ni++){
        #pragma unroll
        for(int r=0; r<4; r++){
            int m = m0 + wm*64 + mi*16 + g*4 + r;   // C/D: row=(lane>>4)*4+reg
            int n = n0 + wn*64 + ni*16 + c;         // C/D: col=lane&15
            if(m >= M_) continue;
            int nl = n - seg*768;
            float val = acc[mi][ni][r] + bias[nl];
            if(mode==3){
                of[(size_t)m*768 + n] = val;
            } else {
                int s = m % S_, b = m / S_;
                int h = nl >> 6, d = nl & 63;
                if(seg==2)      ovt[(((size_t)b*NH_+h)*HD_ + d)*SKPAD + s] = (short)f2bf(val);
                else if(seg==1) ok [(((size_t)b*NH_+h)*SKPAD + s)*HD_ + d] = (short)f2bf(val);
                else            oq [(((size_t)b*NH_+h)*S_ + s)*HD_ + d] = (short)f2bf(val);
            }
        }
    }
}

// flash attention: grid (bh, qtile) -> bh%8 pins same-head blocks to one XCD's L2.
// K/V double-buffered via global_load_lds + counted vmcnt; softmax in exp2 domain;
// row-sum via all-ones MFMA (lands in l_run[] layout for free).
__global__ __launch_bounds__(256) void k_attn(
    const short* __restrict__ qh, const short* __restrict__ kh, const short* __restrict__ vt,
    short* __restrict__ ctx)
{
    __shared__ short lK[2][64*64], lV[2][64*64], lP[4*16*64];
    const int t = threadIdx.x;
    const int w = t>>6, lane = t&63, g = lane>>4, c = lane&15;
    const int bh = blockIdx.x, b = bh/NH_, h = bh%NH_;
    const int q0 = blockIdx.y*64;

    // per-wave Q staging into own lP region (guarded), then frags to regs
    #pragma unroll
    for(int i=0;i<2;i++){
        int row = i*8 + (lane>>3);
        int e8 = (lane&7)*8;
        int s = q0 + w*16 + row;
        short8 v = {};
        if(s < S_) v = *(const short8*)&qh[((size_t)bh*S_ + s)*HD_ + e8];
        *(short8*)&lP[w*1024 + row*64 + (e8 ^ ((row&7)<<3))] = v;
    }
    short8 qf[2];
    #pragma unroll
    for(int ks=0; ks<2; ks++)
        qf[ks] = *(const short8*)&lP[w*1024 + c*64 + ((ks*32+g*8) ^ ((c&7)<<3))];

    short8 ones;
    #pragma unroll
    for(int j=0;j<8;j++) ones[j] = (short)0x3F80;    // bf16 1.0

    const int srow = lane>>3;
    const int sw8 = ((lane&7) ^ srow)*8;
    const short* pk0 = kh + ((size_t)bh*SKPAD + w*16 + srow)*64 + sw8;
    const short* pv0 = vt + ((size_t)bh*64 + w*16 + srow)*SKPAD + sw8;

    // prologue: stage tile 0 into buffer 0
    #pragma unroll
    for(int i=0;i<2;i++){
        gload_lds16(pk0 + i*8*64,    &lK[0][(w*16+i*8)*64]);
        gload_lds16(pv0 + i*8*SKPAD, &lV[0][(w*16+i*8)*64]);
    }

    float m_run[4], l_run[4];
    f32x4 O[4] = {};
    #pragma unroll
    for(int r=0;r<4;r++){ m_run[r] = -3e38f; l_run[r] = 0.f; }

    int bb = 0;
    for(int kt=0; kt<10; kt++){
        if(kt<9){
            const short* pk = pk0 + (kt+1)*4096;   // 64 rows * 64
            const short* pv = pv0 + (kt+1)*64;     // 64 cols
            #pragma unroll
            for(int i=0;i<2;i++){
                gload_lds16(pk + i*8*64,    &lK[bb^1][(w*16+i*8)*64]);
                gload_lds16(pv + i*8*SKPAD, &lV[bb^1][(w*16+i*8)*64]);
            }
            asm volatile("s_waitcnt vmcnt(4)" ::: "memory");
        } else {
            asm volatile("s_waitcnt vmcnt(0)" ::: "memory");
        }
        __builtin_amdgcn_s_barrier();
        asm volatile("" ::: "memory");

        const short* LK = lK[bb]; const short* LV = lV[bb];

        // S = Q K^T (per wave: 16 q-rows x 64 keys), scaled into log2 domain
        float sv[4][4];
        #pragma unroll
        for(int nt=0; nt<4; nt++){
            f32x4 sa = {};
            int row = nt*16 + c;
            int rx = (row&7)<<3;
            #pragma unroll
            for(int ks=0; ks<2; ks++){
                short8 kf = *(const short8*)&LK[row*64 + ((ks*32+g*8) ^ rx)];
                sa = __builtin_amdgcn_mfma_f32_16x16x32_bf16(qf[ks], kf, sa, 0,0,0);
            }
            #pragma unroll
            for(int r=0;r<4;r++) sv[nt][r] = sa[r]*0.18033688011f;  // /8 * log2(e)
        }
        if(kt==9){
            #pragma unroll
            for(int nt=0; nt<4; nt++){
                int key = 576 + nt*16 + c;
                if(key >= S_){
                    #pragma unroll
                    for(int r=0;r<4;r++) sv[nt][r] = -3e38f;
                }
            }
        }
        // online softmax: max via shuffles (rows on 16 c-lanes), sum via ones-MFMA
        float fac[4];
        #pragma unroll
        for(int r=0;r<4;r++){
            float mx = fmaxf(fmaxf(sv[0][r],sv[1][r]),fmaxf(sv[2][r],sv[3][r]));
            for(int off=1; off<16; off<<=1) mx = fmaxf(mx, __shfl_xor(mx, off));
            float nm = fmaxf(m_run[r], mx);
            fac[r] = __builtin_amdgcn_exp2f(m_run[r] - nm);
            m_run[r] = nm;
        }
        #pragma unroll
        for(int nt=0; nt<4; nt++){
            #pragma unroll
            for(int r=0;r<4;r++){
                float p = __builtin_amdgcn_exp2f(sv[nt][r] - m_run[r]);
                int prow = g*4 + r;
                lP[w*1024 + prow*64 + ((nt*16 + c) ^ ((prow&7)<<3))] = (short)f2bf(p);
            }
        }
        // P fragments (own-wave LDS region)
        short8 pf[2];
        #pragma unroll
        for(int ks=0; ks<2; ks++)
            pf[ks] = *(const short8*)&lP[w*1024 + c*64 + ((ks*32+g*8) ^ ((c&7)<<3))];
        // row-sum = P . 1  (output row = g*4+r matches l_run indexing)
        f32x4 rs = {};
        rs = __builtin_amdgcn_mfma_f32_16x16x32_bf16(pf[0], ones, rs, 0,0,0);
        rs = __builtin_amdgcn_mfma_f32_16x16x32_bf16(pf[1], ones, rs, 0,0,0);
        #pragma unroll
        for(int r=0;r<4;r++) l_run[r] = l_run[r]*fac[r] + rs[r];
        #pragma unroll
        for(int nt=0;nt<4;nt++)
            #pragma unroll
            for(int r=0;r<4;r++) O[nt][r] *= fac[r];

        // O += P V  (V^T tile rows = d)
        #pragma unroll
        for(int nt=0; nt<4; nt++){
            int vrow = nt*16 + c;
            int rx = (vrow&7)<<3;
            #pragma unroll
            for(int ks=0; ks<2; ks++){
                short8 vf = *(const short8*)&LV[vrow*64 + ((ks*32+g*8) ^ rx)];
                O[nt] = __builtin_amdgcn_mfma_f32_16x16x32_bf16(pf[ks], vf, O[nt], 0,0,0);
            }
        }
        asm volatile("s_waitcnt lgkmcnt(0)" ::: "memory");
        __builtin_amdgcn_s_barrier();
        asm volatile("" ::: "memory");
        bb ^= 1;
    }

    #pragma unroll
    for(int nt=0; nt<4; nt++){
        #pragma unroll
        for(int r=0;r<4;r++){
            int s = q0 + w*16 + g*4 + r;
            if(s < S_){
                float val = O[nt][r] / l_run[r];
                ctx[((size_t)b*S_ + s)*H_ + h*HD_ + nt*16 + c] = (short)f2bf(val);
            }
        }
    }
}

extern "C" void kernel_launch(void* const* d_in, const int* in_sizes, int n_in,
                              void* d_out, int out_size, void* d_ws, size_t ws_size,
                              hipStream_t stream)
{
    const float* hs = (const float*)d_in[0];
    const float* Wq = (const float*)d_in[1];
    const float* bq = (const float*)d_in[2];
    const float* Wk = (const float*)d_in[3];
    const float* bk = (const float*)d_in[4];
    const float* Wv = (const float*)d_in[5];
    const float* bv = (const float*)d_in[6];
    const float* Wo = (const float*)d_in[7];
    const float* bo = (const float*)d_in[8];
    float* out = (float*)d_out;

    char* ws = (char*)d_ws;
    // abf/ctx: 4736*768*2 = 7,274,496
    // Wt x4:   768*768*2  = 1,179,648 each, contiguous -> fused [2304][768] at wqt
    // qh: 96*577*64*2 = 7,090,176 ; kh: 96*640*64*2 = 7,864,320 ; vt: 96*64*640*2 = 7,864,320
    short* abf = (short*)(ws);
    short* ctx = abf;                               // reuse after QKV GEMM
    short* wqt = (short*)(ws + 7274496);
    short* wkt = (short*)(ws + 7274496 + 1179648);
    short* wvt = (short*)(ws + 7274496 + 2*1179648);
    short* wot = (short*)(ws + 7274496 + 3*1179648);
    short* qh  = (short*)(ws + 11993088);
    short* kh  = (short*)(ws + 19083264);
    short* vt  = (short*)(ws + 26947584);
    // total: 34,811,904 B

    k_cvt<<<1776, 256, 0, stream>>>(hs, abf);
    k_wt<<<dim3(12,12,4), 256, 0, stream>>>(Wq,Wk,Wv,Wo, wqt,wkt,wvt,wot);
    k_pad<<<381, 256, 0, stream>>>(kh, vt);
    k_gemm<<<666, 256, 0, stream>>>(abf, wqt, bq,bk,bv, qh,kh,vt, nullptr, 0, 18);
    k_attn<<<dim3(96,10), 256, 0, stream>>>(qh, kh, vt, ctx);
    k_gemm<<<222, 256, 0, stream>>>(ctx, wot, bo,bo,bo, nullptr,nullptr,nullptr, out, 3, 6);
}

// Round 5
// 117.693 us; speedup vs baseline: 1.3200x; 1.3017x over previous
//
#include <hip/hip_runtime.h>
#include <hip/hip_bf16.h>

// out = softmax((X Wq + bq)(X Wk + bk)^T / 8) (X Wv + bv) Wo + bo
// All prune/straight-through ops in the reference are value-wise identity.
//
// Pipeline (all bf16 MFMA 16x16x32, fp32 accum):
//   k_cvt : hs fp32 -> bf16 A [4736][768]   (rows 4616..4735 zero pad)
//   k_wt  : W fp32 [k][n] -> bf16 Wt [n][k]  (x4, contiguous -> fused [2304][768])
//   k_pad : zero kh pad rows [577,640) and vt pad cols [576,640)
//   k_gemm: fused QKV GEMM (N=2304), 128x128 tile, single-buffer gload_lds,
//           XCD-chunked swizzle; epilogue stages output tile in LDS (V transposed)
//           so ALL global stores are 16B coalesced. mode 3 = ctx@Wo+bo -> fp32
//   k_attn: flash attention, K/V double-buffered gload_lds (counted vmcnt),
//           XCD-pinned grid (bh%8), exp2-domain softmax, MFMA row-sum

#define B_ 8
#define S_ 577
#define H_ 768
#define NH_ 12
#define HD_ 64
#define M_ (B_*S_)     /* 4616 */
#define MPAD 4736      /* 37*128 */
#define BH_ (B_*NH_)   /* 96 */
#define SKPAD 640      /* padded key count */
#define LTS 136        /* padded LDS row stride (shorts) for epilogue tile */

typedef __attribute__((ext_vector_type(8))) short short8;
typedef __attribute__((ext_vector_type(4))) short s16x4;
typedef __attribute__((ext_vector_type(4))) float f32x4;

__device__ inline unsigned short f2bf(float f){
    unsigned int u = __float_as_uint(f);
    u = u + 0x7fffu + ((u>>16)&1u);     // round-to-nearest-even
    return (unsigned short)(u>>16);
}

__device__ inline void gload_lds16(const short* g, short* l){
    __builtin_amdgcn_global_load_lds((const __attribute__((address_space(1))) void*)g,
                                     (__attribute__((address_space(3))) void*)l, 16, 0, 0);
}

// convert hs -> bf16, zero the pad rows [4616..4736)
__global__ __launch_bounds__(256) void k_cvt(const float* __restrict__ x, short* __restrict__ y){
    int i = blockIdx.x*256 + threadIdx.x;
    if(blockIdx.x >= 1731){                // pad region: 45 blocks
        *(short8*)(y + (size_t)i*8) = (short8){};
        return;
    }
    const float4* p = (const float4*)(x + (size_t)i*8);
    float4 a = p[0], b = p[1];
    short8 v;
    v[0]=(short)f2bf(a.x); v[1]=(short)f2bf(a.y); v[2]=(short)f2bf(a.z); v[3]=(short)f2bf(a.w);
    v[4]=(short)f2bf(b.x); v[5]=(short)f2bf(b.y); v[6]=(short)f2bf(b.z); v[7]=(short)f2bf(b.w);
    *(short8*)(y + (size_t)i*8) = v;
}

// transpose + convert: T[n][k] = bf16(W[k][n])
__global__ __launch_bounds__(256) void k_wt(const float* __restrict__ Wq, const float* __restrict__ Wk,
                                            const float* __restrict__ Wv, const float* __restrict__ Wo,
                                            short* __restrict__ Tq, short* __restrict__ Tk,
                                            short* __restrict__ Tv, short* __restrict__ To){
    const float* W = blockIdx.z==0?Wq: blockIdx.z==1?Wk: blockIdx.z==2?Wv:Wo;
    short*       T = blockIdx.z==0?Tq: blockIdx.z==1?Tk: blockIdx.z==2?Tv:To;
    __shared__ float lds[64][65];
    int t = threadIdx.x;
    int k0 = blockIdx.x*64, n0 = blockIdx.y*64;
    for(int i=0;i<4;i++){
        int row = i*16 + (t>>4);
        int col = (t&15)*4;
        float4 v = *(const float4*)&W[(k0+row)*768 + n0 + col];
        lds[row][col]=v.x; lds[row][col+1]=v.y; lds[row][col+2]=v.z; lds[row][col+3]=v.w;
    }
    __syncthreads();
    for(int i=0;i<4;i++){
        int n = i*16 + (t>>4);
        int k4 = (t&15)*4;
        for(int j=0;j<4;j++)
            T[(n0+n)*768 + k0 + k4 + j] = (short)f2bf(lds[k4+j][n]);
    }
}

// zero kh pad rows [577,640) and vt pad cols [576,640)
__global__ __launch_bounds__(256) void k_pad(short* __restrict__ kh, short* __restrict__ vt){
    int tid = blockIdx.x*256 + threadIdx.x;
    short8 z = {};
    if(tid < 48384){                       // 96*63 rows * 8 chunks
        int row_id = tid>>3, ch = tid&7;
        int bh = row_id/63, r = row_id - bh*63;
        *(short8*)&kh[((size_t)bh*SKPAD + 577 + r)*64 + ch*8] = z;
    } else if(tid < 97536){                // 96*64 rows * 8 chunks
        int j = tid - 48384;
        int row_id = j>>3, ch = j&7;
        int bh = row_id>>6, d = row_id&63;
        *(short8*)&vt[((size_t)bh*64 + d)*SKPAD + 576 + ch*8] = z;
    }
}

// 128x128 tile GEMM, single-buffer m97 structure, XCD-chunked swizzle.
// mode 0: A[4736][768] @ Tqkv[2304][768]^T -> q/k/v (routed by n-segment)
// mode 3: A=ctx @ To[768][768]^T + bo -> of fp32
__global__ __launch_bounds__(256) void k_gemm(
    const short* __restrict__ A, const short* __restrict__ T,
    const float* __restrict__ b0, const float* __restrict__ b1, const float* __restrict__ b2,
    short* __restrict__ oq, short* __restrict__ ok, short* __restrict__ ovt,
    float* __restrict__ of, int mode, int NT)
{
    __shared__ short sh[128*LTS];          // 34816B; K-loop uses [0,16384) as lA|lB
    short* lA = sh;
    short* lB = sh + 8192;
    const int t = threadIdx.x;

    // bijective XCD-chunked swizzle (m204): contiguous wg ranges per XCD
    const int nwg = gridDim.x;
    const int q8 = nwg>>3, r8 = nwg&7;
    const int xcd = blockIdx.x&7, cidx = blockIdx.x>>3;
    const int wg = (xcd<r8 ? xcd*(q8+1) : r8*(q8+1) + (xcd-r8)*q8) + cidx;
    const int mt = wg/NT, ntile = wg - mt*NT;
    const int m0 = mt*128, n0 = ntile*128;

    const int seg = (mode==3)? 0 : n0/768;           // block-uniform
    const float* bias = (mode==3)? b0 : (seg==0?b0: seg==1?b1:b2);
    const int nlb = (mode==3)? n0 : n0 - seg*768;

    const int w = t>>6, lane = t&63, g = lane>>4, c = lane&15;
    const int wm = w>>1, wn = w&1;

    // staging: lane l -> row (l>>3), dest 16B-slot (l&7); source chunk (l&7)^(row&7)
    // so LDS[row][slot] = G[row][slot ^ (row&7)]  (XOR-swizzled, conflict-free reads)
    const int lrow = lane>>3;
    const int lcol = ((lane&7) ^ lrow) * 8;
    const short* pa = A + (size_t)(m0 + w*32 + lrow)*768 + lcol;
    const short* pb = T + (size_t)(n0 + w*32 + lrow)*768 + lcol;

    f32x4 acc[4][4] = {};

    for(int kk=0; kk<12; kk++){
        #pragma unroll
        for(int i=0;i<4;i++){
            gload_lds16(pa + (size_t)i*8*768 + kk*64, &lA[(w*32+i*8)*64]);
            gload_lds16(pb + (size_t)i*8*768 + kk*64, &lB[(w*32+i*8)*64]);
        }
        __syncthreads();

        short8 af[4][2], bfv[4][2];
        #pragma unroll
        for(int mi=0; mi<4; mi++){
            int row = wm*64 + mi*16 + c;
            int rx = (row&7)<<3;
            af[mi][0] = *(const short8*)&lA[row*64 + ((g*8) ^ rx)];
            af[mi][1] = *(const short8*)&lA[row*64 + ((32 + g*8) ^ rx)];
        }
        #pragma unroll
        for(int ni=0; ni<4; ni++){
            int row = wn*64 + ni*16 + c;
            int rx = (row&7)<<3;
            bfv[ni][0] = *(const short8*)&lB[row*64 + ((g*8) ^ rx)];
            bfv[ni][1] = *(const short8*)&lB[row*64 + ((32 + g*8) ^ rx)];
        }
        #pragma unroll
        for(int mi=0; mi<4; mi++)
            #pragma unroll
            for(int ni=0; ni<4; ni++){
                acc[mi][ni] = __builtin_amdgcn_mfma_f32_16x16x32_bf16(af[mi][0], bfv[ni][0], acc[mi][ni], 0,0,0);
                acc[mi][ni] = __builtin_amdgcn_mfma_f32_16x16x32_bf16(af[mi][1], bfv[ni][1], acc[mi][ni], 0,0,0);
            }
        __syncthreads();
    }

    if(mode==3){
        #pragma unroll
        for(int mi=0; mi<4; mi++) for(int ni=0; ni<4; ni++){
            #pragma unroll
            for(int r=0; r<4; r++){
                int m = m0 + wm*64 + mi*16 + g*4 + r;   // C/D: row=(lane>>4)*4+reg
                int n = n0 + wn*64 + ni*16 + c;         // C/D: col=lane&15
                if(m >= M_) continue;
                of[(size_t)m*768 + n] = acc[mi][ni][r] + bias[n];
            }
        }
        return;
    }

    // mode 0 epilogue: stage bf16 tile to LDS (V-segment transposed), then
    // 16B-coalesced stores. LDS tile [128][LTS] reuses the staging buffer.
    if(seg==2){
        #pragma unroll
        for(int mi=0;mi<4;mi++)
            #pragma unroll
            for(int ni=0;ni<4;ni++){
                int nl_ = wn*64 + ni*16 + c;
                float bv = bias[nlb + nl_];
                s16x4 pk;
                #pragma unroll
                for(int r=0;r<4;r++) pk[r] = (short)f2bf(acc[mi][ni][r] + bv);
                int ml0 = wm*64 + mi*16 + g*4;
                *(s16x4*)&sh[nl_*LTS + ml0] = pk;       // transposed: [n][m]
            }
    } else {
        #pragma unroll
        for(int mi=0;mi<4;mi++)
            #pragma unroll
            for(int ni=0;ni<4;ni++){
                int nl_ = wn*64 + ni*16 + c;
                float bv = bias[nlb + nl_];
                #pragma unroll
                for(int r=0;r<4;r++){
                    int ml = wm*64 + mi*16 + g*4 + r;
                    sh[ml*LTS + nl_] = (short)f2bf(acc[mi][ni][r] + bv);
                }
            }
    }
    __syncthreads();

    #pragma unroll
    for(int i=0;i<8;i++){
        int idx = i*256 + t;
        int rp = idx>>4, ch = idx&15;
        short8 v8 = *(const short8*)&sh[rp*LTS + ch*8];
        if(seg==2){
            // rows rp = local d over 2 heads; cols = m (s)
            int nl = nlb + rp, hh = nl>>6, dd = nl&63;
            int mg = m0 + ch*8;
            if(mg < M_){
                int b0_ = mg/S_, s0 = mg - b0_*S_;
                if(s0+7 < S_ && mg+7 < M_){
                    *(short8*)&ovt[(((size_t)b0_*NH_+hh)*HD_+dd)*SKPAD + s0] = v8;
                } else {
                    for(int j=0;j<8;j++){
                        int m=mg+j;
                        if(m<M_){ int bj=m/S_, sj=m-bj*S_;
                            ovt[(((size_t)bj*NH_+hh)*HD_+dd)*SKPAD+sj]=v8[j]; }
                    }
                }
            }
        } else {
            int m = m0 + rp;
            if(m < M_){
                int b0_ = m/S_, s0 = m - b0_*S_;
                int nl = nlb + ch*8, hh = nl>>6, dd = nl&63;
                if(seg==1) *(short8*)&ok[(((size_t)b0_*NH_+hh)*SKPAD + s0)*HD_ + dd] = v8;
                else       *(short8*)&oq[(((size_t)b0_*NH_+hh)*S_   + s0)*HD_ + dd] = v8;
            }
        }
    }
}

// flash attention: grid (bh, qtile) -> bh%8 pins same-head blocks to one XCD's L2.
// K/V double-buffered via global_load_lds + counted vmcnt; softmax in exp2 domain;
// row-sum via all-ones MFMA (lands in l_run[] layout for free).
__global__ __launch_bounds__(256) void k_attn(
    const short* __restrict__ qh, const short* __restrict__ kh, const short* __restrict__ vt,
    short* __restrict__ ctx)
{
    __shared__ short lK[2][64*64], lV[2][64*64], lP[4*16*64];
    const int t = threadIdx.x;
    const int w = t>>6, lane = t&63, g = lane>>4, c = lane&15;
    const int bh = blockIdx.x, b = bh/NH_, h = bh%NH_;
    const int q0 = blockIdx.y*64;

    // per-wave Q staging into own lP region (guarded), then frags to regs
    #pragma unroll
    for(int i=0;i<2;i++){
        int row = i*8 + (lane>>3);
        int e8 = (lane&7)*8;
        int s = q0 + w*16 + row;
        short8 v = {};
        if(s < S_) v = *(const short8*)&qh[((size_t)bh*S_ + s)*HD_ + e8];
        *(short8*)&lP[w*1024 + row*64 + (e8 ^ ((row&7)<<3))] = v;
    }
    short8 qf[2];
    #pragma unroll
    for(int ks=0; ks<2; ks++)
        qf[ks] = *(const short8*)&lP[w*1024 + c*64 + ((ks*32+g*8) ^ ((c&7)<<3))];

    short8 ones;
    #pragma unroll
    for(int j=0;j<8;j++) ones[j] = (short)0x3F80;    // bf16 1.0

    const int srow = lane>>3;
    const int sw8 = ((lane&7) ^ srow)*8;
    const short* pk0 = kh + ((size_t)bh*SKPAD + w*16 + srow)*64 + sw8;
    const short* pv0 = vt + ((size_t)bh*64 + w*16 + srow)*SKPAD + sw8;

    // prologue: stage tile 0 into buffer 0
    #pragma unroll
    for(int i=0;i<2;i++){
        gload_lds16(pk0 + i*8*64,    &lK[0][(w*16+i*8)*64]);
        gload_lds16(pv0 + i*8*SKPAD, &lV[0][(w*16+i*8)*64]);
    }

    float m_run[4], l_run[4];
    f32x4 O[4] = {};
    #pragma unroll
    for(int r=0;r<4;r++){ m_run[r] = -3e38f; l_run[r] = 0.f; }

    int bb = 0;
    for(int kt=0; kt<10; kt++){
        if(kt<9){
            const short* pk = pk0 + (kt+1)*4096;   // 64 rows * 64
            const short* pv = pv0 + (kt+1)*64;     // 64 cols
            #pragma unroll
            for(int i=0;i<2;i++){
                gload_lds16(pk + i*8*64,    &lK[bb^1][(w*16+i*8)*64]);
                gload_lds16(pv + i*8*SKPAD, &lV[bb^1][(w*16+i*8)*64]);
            }
            asm volatile("s_waitcnt vmcnt(4)" ::: "memory");
        } else {
            asm volatile("s_waitcnt vmcnt(0)" ::: "memory");
        }
        __builtin_amdgcn_s_barrier();
        asm volatile("" ::: "memory");

        const short* LK = lK[bb]; const short* LV = lV[bb];

        // S = Q K^T (per wave: 16 q-rows x 64 keys), scaled into log2 domain
        float sv[4][4];
        #pragma unroll
        for(int nt=0; nt<4; nt++){
            f32x4 sa = {};
            int row = nt*16 + c;
            int rx = (row&7)<<3;
            #pragma unroll
            for(int ks=0; ks<2; ks++){
                short8 kf = *(const short8*)&LK[row*64 + ((ks*32+g*8) ^ rx)];
                sa = __builtin_amdgcn_mfma_f32_16x16x32_bf16(qf[ks], kf, sa, 0,0,0);
            }
            #pragma unroll
            for(int r=0;r<4;r++) sv[nt][r] = sa[r]*0.18033688011f;  // /8 * log2(e)
        }
        if(kt==9){
            #pragma unroll
            for(int nt=0; nt<4; nt++){
                int key = 576 + nt*16 + c;
                if(key >= S_){
                    #pragma unroll
                    for(int r=0;r<4;r++) sv[nt][r] = -3e38f;
                }
            }
        }
        // online softmax: max via shuffles (rows on 16 c-lanes), sum via ones-MFMA
        float fac[4];
        #pragma unroll
        for(int r=0;r<4;r++){
            float mx = fmaxf(fmaxf(sv[0][r],sv[1][r]),fmaxf(sv[2][r],sv[3][r]));
            for(int off=1; off<16; off<<=1) mx = fmaxf(mx, __shfl_xor(mx, off));
            float nm = fmaxf(m_run[r], mx);
            fac[r] = __builtin_amdgcn_exp2f(m_run[r] - nm);
            m_run[r] = nm;
        }
        #pragma unroll
        for(int nt=0; nt<4; nt++){
            #pragma unroll
            for(int r=0;r<4;r++){
                float p = __builtin_amdgcn_exp2f(sv[nt][r] - m_run[r]);
                int prow = g*4 + r;
                lP[w*1024 + prow*64 + ((nt*16 + c) ^ ((prow&7)<<3))] = (short)f2bf(p);
            }
        }
        // P fragments (own-wave LDS region)
        short8 pf[2];
        #pragma unroll
        for(int ks=0; ks<2; ks++)
            pf[ks] = *(const short8*)&lP[w*1024 + c*64 + ((ks*32+g*8) ^ ((c&7)<<3))];
        // row-sum = P . 1  (output row = g*4+r matches l_run indexing)
        f32x4 rs = {};
        rs = __builtin_amdgcn_mfma_f32_16x16x32_bf16(pf[0], ones, rs, 0,0,0);
        rs = __builtin_amdgcn_mfma_f32_16x16x32_bf16(pf[1], ones, rs, 0,0,0);
        #pragma unroll
        for(int r=0;r<4;r++) l_run[r] = l_run[r]*fac[r] + rs[r];
        #pragma unroll
        for(int nt=0;nt<4;nt++)
            #pragma unroll
            for(int r=0;r<4;r++) O[nt][r] *= fac[r];

        // O += P V  (V^T tile rows = d)
        #pragma unroll
        for(int nt=0; nt<4; nt++){
            int vrow = nt*16 + c;
            int rx = (vrow&7)<<3;
            #pragma unroll
            for(int ks=0; ks<2; ks++){
                short8 vf = *(const short8*)&LV[vrow*64 + ((ks*32+g*8) ^ rx)];
                O[nt] = __builtin_amdgcn_mfma_f32_16x16x32_bf16(pf[ks], vf, O[nt], 0,0,0);
            }
        }
        asm volatile("s_waitcnt lgkmcnt(0)" ::: "memory");
        __builtin_amdgcn_s_barrier();
        asm volatile("" ::: "memory");
        bb ^= 1;
    }

    #pragma unroll
    for(int nt=0; nt<4; nt++){
        #pragma unroll
        for(int r=0;r<4;r++){
            int s = q0 + w*16 + g*4 + r;
            if(s < S_){
                float val = O[nt][r] / l_run[r];
                ctx[((size_t)b*S_ + s)*H_ + h*HD_ + nt*16 + c] = (short)f2bf(val);
            }
        }
    }
}

extern "C" void kernel_launch(void* const* d_in, const int* in_sizes, int n_in,
                              void* d_out, int out_size, void* d_ws, size_t ws_size,
                              hipStream_t stream)
{
    const float* hs = (const float*)d_in[0];
    const float* Wq = (const float*)d_in[1];
    const float* bq = (const float*)d_in[2];
    const float* Wk = (const float*)d_in[3];
    const float* bk = (const float*)d_in[4];
    const float* Wv = (const float*)d_in[5];
    const float* bv = (const float*)d_in[6];
    const float* Wo = (const float*)d_in[7];
    const float* bo = (const float*)d_in[8];
    float* out = (float*)d_out;

    char* ws = (char*)d_ws;
    // abf/ctx: 4736*768*2 = 7,274,496
    // Wt x4:   768*768*2  = 1,179,648 each, contiguous -> fused [2304][768] at wqt
    // qh: 96*577*64*2 = 7,090,176 ; kh: 96*640*64*2 = 7,864,320 ; vt: 96*64*640*2 = 7,864,320
    short* abf = (short*)(ws);
    short* ctx = abf;                               // reuse after QKV GEMM
    short* wqt = (short*)(ws + 7274496);
    short* wkt = (short*)(ws + 7274496 + 1179648);
    short* wvt = (short*)(ws + 7274496 + 2*1179648);
    short* wot = (short*)(ws + 7274496 + 3*1179648);
    short* qh  = (short*)(ws + 11993088);
    short* kh  = (short*)(ws + 19083264);
    short* vt  = (short*)(ws + 26947584);
    // total: 34,811,904 B

    k_cvt<<<1776, 256, 0, stream>>>(hs, abf);
    k_wt<<<dim3(12,12,4), 256, 0, stream>>>(Wq,Wk,Wv,Wo, wqt,wkt,wvt,wot);
    k_pad<<<381, 256, 0, stream>>>(kh, vt);
    k_gemm<<<666, 256, 0, stream>>>(abf, wqt, bq,bk,bv, qh,kh,vt, nullptr, 0, 18);
    k_attn<<<dim3(96,10), 256, 0, stream>>>(qh, kh, vt, ctx);
    k_gemm<<<222, 256, 0, stream>>>(ctx, wot, bo,bo,bo, nullptr,nullptr,nullptr, out, 3, 6);
}

// Round 6
// 104.383 us; speedup vs baseline: 1.4883x; 1.1275x over previous
//
#include <hip/hip_runtime.h>
#include <hip/hip_bf16.h>

// out = softmax((X Wq + bq)(X Wk + bk)^T / 8) (X Wv + bv) Wo + bo
// All prune/straight-through ops in the reference are value-wise identity.
//
// Pipeline (all bf16 MFMA 16x16x32, fp32 accum):
//   k_cvt : hs fp32 -> bf16 A [4736][768]   (rows 4616..4735 zero pad)
//   k_wt  : W fp32 [k][n] -> bf16 Wt [n][k]  (x4, contiguous -> fused [2304][768])
//   k_pad : zero kh pad rows [577,640) and vt pad cols [576,640)
//   k_gemm: fused QKV GEMM (N=2304), 128x128 tile, DOUBLE-BUFFERED gload_lds
//           with counted vmcnt(8) (loads stay in flight across barriers),
//           XCD-chunked swizzle; epilogue stages tile in LDS (V transposed)
//           so all global stores are 16B coalesced. mode 3 = ctx@Wo+bo -> fp32
//   k_attn: flash attention, QBLK=128 (2 q-frags/wave), K/V double-buffered
//           gload_lds (counted vmcnt), XCD-pinned grid (bh%8), exp2 softmax,
//           MFMA row-sum

#define B_ 8
#define S_ 577
#define H_ 768
#define NH_ 12
#define HD_ 64
#define M_ (B_*S_)     /* 4616 */
#define MPAD 4736      /* 37*128 */
#define BH_ (B_*NH_)   /* 96 */
#define SKPAD 640      /* padded key count */
#define LTS 136        /* padded LDS row stride (shorts) for epilogue tile */

typedef __attribute__((ext_vector_type(8))) short short8;
typedef __attribute__((ext_vector_type(4))) short s16x4;
typedef __attribute__((ext_vector_type(4))) float f32x4;

__device__ inline unsigned short f2bf(float f){
    unsigned int u = __float_as_uint(f);
    u = u + 0x7fffu + ((u>>16)&1u);     // round-to-nearest-even
    return (unsigned short)(u>>16);
}

__device__ inline void gload_lds16(const short* g, short* l){
    __builtin_amdgcn_global_load_lds((const __attribute__((address_space(1))) void*)g,
                                     (__attribute__((address_space(3))) void*)l, 16, 0, 0);
}

// convert hs -> bf16, zero the pad rows [4616..4736)
__global__ __launch_bounds__(256) void k_cvt(const float* __restrict__ x, short* __restrict__ y){
    int i = blockIdx.x*256 + threadIdx.x;
    if(blockIdx.x >= 1731){                // pad region: 45 blocks
        *(short8*)(y + (size_t)i*8) = (short8){};
        return;
    }
    const float4* p = (const float4*)(x + (size_t)i*8);
    float4 a = p[0], b = p[1];
    short8 v;
    v[0]=(short)f2bf(a.x); v[1]=(short)f2bf(a.y); v[2]=(short)f2bf(a.z); v[3]=(short)f2bf(a.w);
    v[4]=(short)f2bf(b.x); v[5]=(short)f2bf(b.y); v[6]=(short)f2bf(b.z); v[7]=(short)f2bf(b.w);
    *(short8*)(y + (size_t)i*8) = v;
}

// transpose + convert: T[n][k] = bf16(W[k][n])
__global__ __launch_bounds__(256) void k_wt(const float* __restrict__ Wq, const float* __restrict__ Wk,
                                            const float* __restrict__ Wv, const float* __restrict__ Wo,
                                            short* __restrict__ Tq, short* __restrict__ Tk,
                                            short* __restrict__ Tv, short* __restrict__ To){
    const float* W = blockIdx.z==0?Wq: blockIdx.z==1?Wk: blockIdx.z==2?Wv:Wo;
    short*       T = blockIdx.z==0?Tq: blockIdx.z==1?Tk: blockIdx.z==2?Tv:To;
    __shared__ float lds[64][65];
    int t = threadIdx.x;
    int k0 = blockIdx.x*64, n0 = blockIdx.y*64;
    for(int i=0;i<4;i++){
        int row = i*16 + (t>>4);
        int col = (t&15)*4;
        float4 v = *(const float4*)&W[(k0+row)*768 + n0 + col];
        lds[row][col]=v.x; lds[row][col+1]=v.y; lds[row][col+2]=v.z; lds[row][col+3]=v.w;
    }
    __syncthreads();
    for(int i=0;i<4;i++){
        int n = i*16 + (t>>4);
        int k4 = (t&15)*4;
        for(int j=0;j<4;j++)
            T[(n0+n)*768 + k0 + k4 + j] = (short)f2bf(lds[k4+j][n]);
    }
}

// zero kh pad rows [577,640) and vt pad cols [576,640)
__global__ __launch_bounds__(256) void k_pad(short* __restrict__ kh, short* __restrict__ vt){
    int tid = blockIdx.x*256 + threadIdx.x;
    short8 z = {};
    if(tid < 48384){                       // 96*63 rows * 8 chunks
        int row_id = tid>>3, ch = tid&7;
        int bh = row_id/63, r = row_id - bh*63;
        *(short8*)&kh[((size_t)bh*SKPAD + 577 + r)*64 + ch*8] = z;
    } else if(tid < 97536){                // 96*64 rows * 8 chunks
        int j = tid - 48384;
        int row_id = j>>3, ch = j&7;
        int bh = row_id>>6, d = row_id&63;
        *(short8*)&vt[((size_t)bh*64 + d)*SKPAD + 576 + ch*8] = z;
    }
}

// 128x128 tile GEMM, double-buffered counted-vmcnt K-loop, XCD-chunked swizzle.
// mode 0: A[4736][768] @ Tqkv[2304][768]^T -> q/k/v (routed by n-segment)
// mode 3: A=ctx @ To[768][768]^T + bo -> of fp32
__global__ __launch_bounds__(256) void k_gemm(
    const short* __restrict__ A, const short* __restrict__ T,
    const float* __restrict__ b0, const float* __restrict__ b1, const float* __restrict__ b2,
    short* __restrict__ oq, short* __restrict__ ok, short* __restrict__ ovt,
    float* __restrict__ of, int mode, int NT)
{
    __shared__ short sh[32768];            // 64KB: dbuf K-loop; epilogue reuses [0,17408)
    const int t = threadIdx.x;

    // bijective XCD-chunked swizzle (m204): contiguous wg ranges per XCD
    const int nwg = gridDim.x;
    const int q8 = nwg>>3, r8 = nwg&7;
    const int xcd = blockIdx.x&7, cidx = blockIdx.x>>3;
    const int wg = (xcd<r8 ? xcd*(q8+1) : r8*(q8+1) + (xcd-r8)*q8) + cidx;
    const int mt = wg/NT, ntile = wg - mt*NT;
    const int m0 = mt*128, n0 = ntile*128;

    const int seg = (mode==3)? 0 : n0/768;           // block-uniform
    const float* bias = (mode==3)? b0 : (seg==0?b0: seg==1?b1:b2);
    const int nlb = (mode==3)? n0 : n0 - seg*768;

    const int w = t>>6, lane = t&63, g = lane>>4, c = lane&15;
    const int wm = w>>1, wn = w&1;

    // staging: lane l -> row (l>>3), dest 16B-slot (l&7); source chunk (l&7)^(row&7)
    // so LDS[row][slot] = G[row][slot ^ (row&7)]  (XOR-swizzled, conflict-free reads)
    const int lrow = lane>>3;
    const int lcol = ((lane&7) ^ lrow) * 8;
    const short* pa = A + (size_t)(m0 + w*32 + lrow)*768 + lcol;
    const short* pb = T + (size_t)(n0 + w*32 + lrow)*768 + lcol;

    f32x4 acc[4][4] = {};

    // buffers: buf bb -> lA at sh+bb*16384, lB at sh+bb*16384+8192
    // prologue: stage K-step 0 into buffer 0
    #pragma unroll
    for(int i=0;i<4;i++){
        gload_lds16(pa + (size_t)i*8*768, &sh[(w*32+i*8)*64]);
        gload_lds16(pb + (size_t)i*8*768, &sh[8192 + (w*32+i*8)*64]);
    }
    int bb = 0;
    for(int kk=0; kk<12; kk++){
        if(kk<11){
            short* dstA = &sh[(bb^1)*16384];
            short* dstB = dstA + 8192;
            #pragma unroll
            for(int i=0;i<4;i++){
                gload_lds16(pa + (size_t)i*8*768 + (kk+1)*64, &dstA[(w*32+i*8)*64]);
                gload_lds16(pb + (size_t)i*8*768 + (kk+1)*64, &dstB[(w*32+i*8)*64]);
            }
            asm volatile("s_waitcnt vmcnt(8)" ::: "memory");
        } else {
            asm volatile("s_waitcnt vmcnt(0)" ::: "memory");
        }
        __builtin_amdgcn_s_barrier();
        asm volatile("" ::: "memory");

        const short* LA = &sh[bb*16384];
        const short* LB = LA + 8192;
        short8 af[4][2], bfv[4][2];
        #pragma unroll
        for(int mi=0; mi<4; mi++){
            int row = wm*64 + mi*16 + c;
            int rx = (row&7)<<3;
            af[mi][0] = *(const short8*)&LA[row*64 + ((g*8) ^ rx)];
            af[mi][1] = *(const short8*)&LA[row*64 + ((32 + g*8) ^ rx)];
        }
        #pragma unroll
        for(int ni=0; ni<4; ni++){
            int row = wn*64 + ni*16 + c;
            int rx = (row&7)<<3;
            bfv[ni][0] = *(const short8*)&LB[row*64 + ((g*8) ^ rx)];
            bfv[ni][1] = *(const short8*)&LB[row*64 + ((32 + g*8) ^ rx)];
        }
        #pragma unroll
        for(int mi=0; mi<4; mi++)
            #pragma unroll
            for(int ni=0; ni<4; ni++){
                acc[mi][ni] = __builtin_amdgcn_mfma_f32_16x16x32_bf16(af[mi][0], bfv[ni][0], acc[mi][ni], 0,0,0);
                acc[mi][ni] = __builtin_amdgcn_mfma_f32_16x16x32_bf16(af[mi][1], bfv[ni][1], acc[mi][ni], 0,0,0);
            }
        asm volatile("s_waitcnt lgkmcnt(0)" ::: "memory");
        __builtin_amdgcn_s_barrier();
        asm volatile("" ::: "memory");
        bb ^= 1;
    }

    if(mode==3){
        #pragma unroll
        for(int mi=0; mi<4; mi++) for(int ni=0; ni<4; ni++){
            #pragma unroll
            for(int r=0; r<4; r++){
                int m = m0 + wm*64 + mi*16 + g*4 + r;   // C/D: row=(lane>>4)*4+reg
                int n = n0 + wn*64 + ni*16 + c;         // C/D: col=lane&15
                if(m >= M_) continue;
                of[(size_t)m*768 + n] = acc[mi][ni][r] + bias[n];
            }
        }
        return;
    }

    // mode 0 epilogue: stage bf16 tile to LDS (V-segment transposed), then
    // 16B-coalesced stores. LDS tile [128][LTS] reuses the staging buffer.
    if(seg==2){
        #pragma unroll
        for(int mi=0;mi<4;mi++)
            #pragma unroll
            for(int ni=0;ni<4;ni++){
                int nl_ = wn*64 + ni*16 + c;
                float bv = bias[nlb + nl_];
                s16x4 pk;
                #pragma unroll
                for(int r=0;r<4;r++) pk[r] = (short)f2bf(acc[mi][ni][r] + bv);
                int ml0 = wm*64 + mi*16 + g*4;
                *(s16x4*)&sh[nl_*LTS + ml0] = pk;       // transposed: [n][m]
            }
    } else {
        #pragma unroll
        for(int mi=0;mi<4;mi++)
            #pragma unroll
            for(int ni=0;ni<4;ni++){
                int nl_ = wn*64 + ni*16 + c;
                float bv = bias[nlb + nl_];
                #pragma unroll
                for(int r=0;r<4;r++){
                    int ml = wm*64 + mi*16 + g*4 + r;
                    sh[ml*LTS + nl_] = (short)f2bf(acc[mi][ni][r] + bv);
                }
            }
    }
    __syncthreads();

    #pragma unroll
    for(int i=0;i<8;i++){
        int idx = i*256 + t;
        int rp = idx>>4, ch = idx&15;
        short8 v8 = *(const short8*)&sh[rp*LTS + ch*8];
        if(seg==2){
            // rows rp = local d over 2 heads; cols = m (s)
            int nl = nlb + rp, hh = nl>>6, dd = nl&63;
            int mg = m0 + ch*8;
            if(mg < M_){
                int b0_ = mg/S_, s0 = mg - b0_*S_;
                if(s0+7 < S_ && mg+7 < M_){
                    *(short8*)&ovt[(((size_t)b0_*NH_+hh)*HD_+dd)*SKPAD + s0] = v8;
                } else {
                    for(int j=0;j<8;j++){
                        int m=mg+j;
                        if(m<M_){ int bj=m/S_, sj=m-bj*S_;
                            ovt[(((size_t)bj*NH_+hh)*HD_+dd)*SKPAD+sj]=v8[j]; }
                    }
                }
            }
        } else {
            int m = m0 + rp;
            if(m < M_){
                int b0_ = m/S_, s0 = m - b0_*S_;
                int nl = nlb + ch*8, hh = nl>>6, dd = nl&63;
                if(seg==1) *(short8*)&ok[(((size_t)b0_*NH_+hh)*SKPAD + s0)*HD_ + dd] = v8;
                else       *(short8*)&oq[(((size_t)b0_*NH_+hh)*S_   + s0)*HD_ + dd] = v8;
            }
        }
    }
}

// flash attention: QBLK=128 (each wave owns 32 q-rows = 2 fragments), grid (bh, qtile).
// K/V double-buffered via global_load_lds + counted vmcnt; softmax in exp2 domain;
// row-sum via all-ones MFMA.
__global__ __launch_bounds__(256) void k_attn(
    const short* __restrict__ qh, const short* __restrict__ kh, const short* __restrict__ vt,
    short* __restrict__ ctx)
{
    __shared__ short lK[2][64*64], lV[2][64*64], lP[4*2048];
    const int t = threadIdx.x;
    const int w = t>>6, lane = t&63, g = lane>>4, c = lane&15;
    const int bh = blockIdx.x, b = bh/NH_, h = bh%NH_;
    const int q0 = blockIdx.y*128;

    // per-wave Q staging (32 rows) into own lP region (guarded), then frags to regs
    #pragma unroll
    for(int i=0;i<4;i++){
        int row = i*8 + (lane>>3);
        int e8 = (lane&7)*8;
        int s = q0 + w*32 + row;
        short8 v = {};
        if(s < S_) v = *(const short8*)&qh[((size_t)bh*S_ + s)*HD_ + e8];
        *(short8*)&lP[w*2048 + row*64 + (e8 ^ ((row&7)<<3))] = v;
    }
    short8 qf[2][2];
    #pragma unroll
    for(int qi=0; qi<2; qi++)
        #pragma unroll
        for(int ks=0; ks<2; ks++)
            qf[qi][ks] = *(const short8*)&lP[w*2048 + (qi*16+c)*64 + ((ks*32+g*8) ^ ((c&7)<<3))];

    short8 ones;
    #pragma unroll
    for(int j=0;j<8;j++) ones[j] = (short)0x3F80;    // bf16 1.0

    const int srow = lane>>3;
    const int sw8 = ((lane&7) ^ srow)*8;
    const short* pk0 = kh + ((size_t)bh*SKPAD + w*16 + srow)*64 + sw8;
    const short* pv0 = vt + ((size_t)bh*64 + w*16 + srow)*SKPAD + sw8;

    // prologue: stage tile 0 into buffer 0
    #pragma unroll
    for(int i=0;i<2;i++){
        gload_lds16(pk0 + i*8*64,    &lK[0][(w*16+i*8)*64]);
        gload_lds16(pv0 + i*8*SKPAD, &lV[0][(w*16+i*8)*64]);
    }

    float m_run[2][4], l_run[2][4];
    f32x4 O[2][4] = {};
    #pragma unroll
    for(int qi=0;qi<2;qi++)
        #pragma unroll
        for(int r=0;r<4;r++){ m_run[qi][r] = -3e38f; l_run[qi][r] = 0.f; }

    int bb = 0;
    for(int kt=0; kt<10; kt++){
        if(kt<9){
            const short* pk = pk0 + (kt+1)*4096;   // 64 rows * 64
            const short* pv = pv0 + (kt+1)*64;     // 64 cols
            #pragma unroll
            for(int i=0;i<2;i++){
                gload_lds16(pk + i*8*64,    &lK[bb^1][(w*16+i*8)*64]);
                gload_lds16(pv + i*8*SKPAD, &lV[bb^1][(w*16+i*8)*64]);
            }
            asm volatile("s_waitcnt vmcnt(4)" ::: "memory");
        } else {
            asm volatile("s_waitcnt vmcnt(0)" ::: "memory");
        }
        __builtin_amdgcn_s_barrier();
        asm volatile("" ::: "memory");

        const short* LK = lK[bb]; const short* LV = lV[bb];

        // S = Q K^T (per wave: 2 x 16 q-rows x 64 keys), scaled into log2 domain
        float sv[2][4][4];
        #pragma unroll
        for(int nt=0; nt<4; nt++){
            int row = nt*16 + c;
            int rx = (row&7)<<3;
            short8 kf[2];
            kf[0] = *(const short8*)&LK[row*64 + ((g*8) ^ rx)];
            kf[1] = *(const short8*)&LK[row*64 + ((32+g*8) ^ rx)];
            #pragma unroll
            for(int qi=0; qi<2; qi++){
                f32x4 sa = {};
                sa = __builtin_amdgcn_mfma_f32_16x16x32_bf16(qf[qi][0], kf[0], sa, 0,0,0);
                sa = __builtin_amdgcn_mfma_f32_16x16x32_bf16(qf[qi][1], kf[1], sa, 0,0,0);
                #pragma unroll
                for(int r=0;r<4;r++) sv[qi][nt][r] = sa[r]*0.18033688011f;  // /8 * log2(e)
            }
        }
        if(kt==9){
            #pragma unroll
            for(int nt=0; nt<4; nt++){
                int key = 576 + nt*16 + c;
                if(key >= S_){
                    #pragma unroll
                    for(int qi=0;qi<2;qi++)
                        #pragma unroll
                        for(int r=0;r<4;r++) sv[qi][nt][r] = -3e38f;
                }
            }
        }
        // online softmax: max via shuffles (rows on 16 c-lanes), sum via ones-MFMA
        float fac[2][4];
        #pragma unroll
        for(int qi=0; qi<2; qi++)
            #pragma unroll
            for(int r=0;r<4;r++){
                float mx = fmaxf(fmaxf(sv[qi][0][r],sv[qi][1][r]),fmaxf(sv[qi][2][r],sv[qi][3][r]));
                for(int off=1; off<16; off<<=1) mx = fmaxf(mx, __shfl_xor(mx, off));
                float nm = fmaxf(m_run[qi][r], mx);
                fac[qi][r] = __builtin_amdgcn_exp2f(m_run[qi][r] - nm);
                m_run[qi][r] = nm;
            }
        #pragma unroll
        for(int qi=0; qi<2; qi++)
            #pragma unroll
            for(int nt=0; nt<4; nt++)
                #pragma unroll
                for(int r=0;r<4;r++){
                    float p = __builtin_amdgcn_exp2f(sv[qi][nt][r] - m_run[qi][r]);
                    int prow = g*4 + r;
                    lP[w*2048 + qi*1024 + prow*64 + ((nt*16 + c) ^ ((prow&7)<<3))] = (short)f2bf(p);
                }
        // P fragments (own-wave LDS region)
        short8 pf[2][2];
        #pragma unroll
        for(int qi=0; qi<2; qi++)
            #pragma unroll
            for(int ks=0; ks<2; ks++)
                pf[qi][ks] = *(const short8*)&lP[w*2048 + qi*1024 + c*64 + ((ks*32+g*8) ^ ((c&7)<<3))];
        // row-sum = P . 1  (output row = g*4+r matches l_run indexing)
        #pragma unroll
        for(int qi=0; qi<2; qi++){
            f32x4 rs = {};
            rs = __builtin_amdgcn_mfma_f32_16x16x32_bf16(pf[qi][0], ones, rs, 0,0,0);
            rs = __builtin_amdgcn_mfma_f32_16x16x32_bf16(pf[qi][1], ones, rs, 0,0,0);
            #pragma unroll
            for(int r=0;r<4;r++) l_run[qi][r] = l_run[qi][r]*fac[qi][r] + rs[r];
        }
        #pragma unroll
        for(int qi=0; qi<2; qi++)
            #pragma unroll
            for(int nt=0;nt<4;nt++)
                #pragma unroll
                for(int r=0;r<4;r++) O[qi][nt][r] *= fac[qi][r];

        // O += P V  (V^T tile rows = d; vf reused across both q-frags)
        #pragma unroll
        for(int nt=0; nt<4; nt++){
            int vrow = nt*16 + c;
            int rx = (vrow&7)<<3;
            short8 vf[2];
            vf[0] = *(const short8*)&LV[vrow*64 + ((g*8) ^ rx)];
            vf[1] = *(const short8*)&LV[vrow*64 + ((32+g*8) ^ rx)];
            #pragma unroll
            for(int qi=0; qi<2; qi++){
                O[qi][nt] = __builtin_amdgcn_mfma_f32_16x16x32_bf16(pf[qi][0], vf[0], O[qi][nt], 0,0,0);
                O[qi][nt] = __builtin_amdgcn_mfma_f32_16x16x32_bf16(pf[qi][1], vf[1], O[qi][nt], 0,0,0);
            }
        }
        asm volatile("s_waitcnt lgkmcnt(0)" ::: "memory");
        __builtin_amdgcn_s_barrier();
        asm volatile("" ::: "memory");
        bb ^= 1;
    }

    #pragma unroll
    for(int qi=0; qi<2; qi++)
        #pragma unroll
        for(int nt=0; nt<4; nt++)
            #pragma unroll
            for(int r=0;r<4;r++){
                int s = q0 + w*32 + qi*16 + g*4 + r;
                if(s < S_){
                    float val = O[qi][nt][r] / l_run[qi][r];
                    ctx[((size_t)b*S_ + s)*H_ + h*HD_ + nt*16 + c] = (short)f2bf(val);
                }
            }
}

extern "C" void kernel_launch(void* const* d_in, const int* in_sizes, int n_in,
                              void* d_out, int out_size, void* d_ws, size_t ws_size,
                              hipStream_t stream)
{
    const float* hs = (const float*)d_in[0];
    const float* Wq = (const float*)d_in[1];
    const float* bq = (const float*)d_in[2];
    const float* Wk = (const float*)d_in[3];
    const float* bk = (const float*)d_in[4];
    const float* Wv = (const float*)d_in[5];
    const float* bv = (const float*)d_in[6];
    const float* Wo = (const float*)d_in[7];
    const float* bo = (const float*)d_in[8];
    float* out = (float*)d_out;

    char* ws = (char*)d_ws;
    // abf/ctx: 4736*768*2 = 7,274,496
    // Wt x4:   768*768*2  = 1,179,648 each, contiguous -> fused [2304][768] at wqt
    // qh: 96*577*64*2 = 7,090,176 ; kh: 96*640*64*2 = 7,864,320 ; vt: 96*64*640*2 = 7,864,320
    short* abf = (short*)(ws);
    short* ctx = abf;                               // reuse after QKV GEMM
    short* wqt = (short*)(ws + 7274496);
    short* wkt = (short*)(ws + 7274496 + 1179648);
    short* wvt = (short*)(ws + 7274496 + 2*1179648);
    short* wot = (short*)(ws + 7274496 + 3*1179648);
    short* qh  = (short*)(ws + 11993088);
    short* kh  = (short*)(ws + 19083264);
    short* vt  = (short*)(ws + 26947584);
    // total: 34,811,904 B

    k_cvt<<<1776, 256, 0, stream>>>(hs, abf);
    k_wt<<<dim3(12,12,4), 256, 0, stream>>>(Wq,Wk,Wv,Wo, wqt,wkt,wvt,wot);
    k_pad<<<381, 256, 0, stream>>>(kh, vt);
    k_gemm<<<666, 256, 0, stream>>>(abf, wqt, bq,bk,bv, qh,kh,vt, nullptr, 0, 18);
    k_attn<<<dim3(96,5), 256, 0, stream>>>(qh, kh, vt, ctx);
    k_gemm<<<222, 256, 0, stream>>>(ctx, wot, bo,bo,bo, nullptr,nullptr,nullptr, out, 3, 6);
}

// Round 7
// 91.858 us; speedup vs baseline: 1.6912x; 1.1364x over previous
//
#include <hip/hip_runtime.h>
#include <hip/hip_bf16.h>

// out = softmax((X Wq + bq)(X Wk + bk)^T / 8) (X Wv + bv) Wo + bo
// All prune/straight-through ops in the reference are value-wise identity.
//
// Pipeline (all bf16 MFMA 16x16x32, fp32 accum):
//   k_prep: fused {hs->bf16 A [4736][768] w/ zero pad | W^T bf16 x4 | kh/vt pad zero}
//   k_gemm: fused QKV GEMM (N=2304), 128x128 tile, 512 threads (8 waves,
//           per-wave 32x64), DOUBLE-BUFFERED gload_lds with counted vmcnt(4),
//           XCD-chunked swizzle; epilogue stages tile in LDS (V transposed)
//           so all global stores are 16B coalesced. mode 3 = ctx@Wo+bo -> fp32
//   k_attn: flash attention, QBLK=128 (2 q-frags/wave), K/V double-buffered
//           gload_lds (counted vmcnt), XCD-pinned grid (bh%8), exp2 softmax,
//           MFMA row-sum, setprio around MFMA clusters

#define B_ 8
#define S_ 577
#define H_ 768
#define NH_ 12
#define HD_ 64
#define M_ (B_*S_)     /* 4616 */
#define MPAD 4736      /* 37*128 */
#define BH_ (B_*NH_)   /* 96 */
#define SKPAD 640      /* padded key count */
#define LTS 136        /* padded LDS row stride (shorts) for epilogue tile */

typedef __attribute__((ext_vector_type(8))) short short8;
typedef __attribute__((ext_vector_type(4))) short s16x4;
typedef __attribute__((ext_vector_type(4))) float f32x4;

__device__ inline unsigned short f2bf(float f){
    unsigned int u = __float_as_uint(f);
    u = u + 0x7fffu + ((u>>16)&1u);     // round-to-nearest-even
    return (unsigned short)(u>>16);
}

__device__ inline void gload_lds16(const short* g, short* l){
    __builtin_amdgcn_global_load_lds((const __attribute__((address_space(1))) void*)g,
                                     (__attribute__((address_space(3))) void*)l, 16, 0, 0);
}

// fused prep: blocks [0,1776) cvt | [1776,2352) wt | [2352,2733) pad
__global__ __launch_bounds__(256) void k_prep(
    const float* __restrict__ hs, short* __restrict__ abf,
    const float* __restrict__ Wq, const float* __restrict__ Wk,
    const float* __restrict__ Wv, const float* __restrict__ Wo,
    short* __restrict__ Tq, short* __restrict__ Tk,
    short* __restrict__ Tv, short* __restrict__ To,
    short* __restrict__ kh, short* __restrict__ vt)
{
    const int bid = blockIdx.x, t = threadIdx.x;
    if(bid < 1776){
        // hs fp32 -> bf16, zero rows [4616,4736)
        int i = bid*256 + t;
        if(bid >= 1731){ *(short8*)(abf + (size_t)i*8) = (short8){}; return; }
        const float4* p = (const float4*)(hs + (size_t)i*8);
        float4 a = p[0], b = p[1];
        short8 v;
        v[0]=(short)f2bf(a.x); v[1]=(short)f2bf(a.y); v[2]=(short)f2bf(a.z); v[3]=(short)f2bf(a.w);
        v[4]=(short)f2bf(b.x); v[5]=(short)f2bf(b.y); v[6]=(short)f2bf(b.z); v[7]=(short)f2bf(b.w);
        *(short8*)(abf + (size_t)i*8) = v;
    } else if(bid < 2352){
        // W [k][n] fp32 -> T [n][k] bf16
        int zidx = bid - 1776;
        int z = zidx & 3, rem = zidx >> 2;        // rem in [0,144)
        int kx = rem % 12, ny = rem / 12;
        const float* W = z==0?Wq: z==1?Wk: z==2?Wv:Wo;
        short*       T = z==0?Tq: z==1?Tk: z==2?Tv:To;
        __shared__ float lds[64][65];
        int k0 = kx*64, n0 = ny*64;
        for(int i=0;i<4;i++){
            int row = i*16 + (t>>4);
            int col = (t&15)*4;
            float4 v = *(const float4*)&W[(k0+row)*768 + n0 + col];
            lds[row][col]=v.x; lds[row][col+1]=v.y; lds[row][col+2]=v.z; lds[row][col+3]=v.w;
        }
        __syncthreads();
        for(int i=0;i<4;i++){
            int n = i*16 + (t>>4);
            int k4 = (t&15)*4;
            for(int j=0;j<4;j++)
                T[(n0+n)*768 + k0 + k4 + j] = (short)f2bf(lds[k4+j][n]);
        }
    } else {
        // zero kh rows [577,640), vt cols [576,640)
        int tid = (bid-2352)*256 + t;
        short8 z = {};
        if(tid < 48384){
            int row_id = tid>>3, ch = tid&7;
            int bh = row_id/63, r = row_id - bh*63;
            *(short8*)&kh[((size_t)bh*SKPAD + 577 + r)*64 + ch*8] = z;
        } else if(tid < 97536){
            int j = tid - 48384;
            int row_id = j>>3, ch = j&7;
            int bh = row_id>>6, d = row_id&63;
            *(short8*)&vt[((size_t)bh*64 + d)*SKPAD + 576 + ch*8] = z;
        }
    }
}

// 128x128 tile GEMM, 512 threads / 8 waves (per-wave 32x64), double-buffered
// counted-vmcnt K-loop, XCD-chunked swizzle.
// mode 0: A[4736][768] @ Tqkv[2304][768]^T -> q/k/v (routed by n-segment)
// mode 3: A=ctx @ To[768][768]^T + bo -> of fp32
__global__ __launch_bounds__(512) void k_gemm(
    const short* __restrict__ A, const short* __restrict__ T,
    const float* __restrict__ b0, const float* __restrict__ b1, const float* __restrict__ b2,
    short* __restrict__ oq, short* __restrict__ ok, short* __restrict__ ovt,
    float* __restrict__ of, int mode, int NT)
{
    __shared__ short sh[32768];            // 64KB: dbuf K-loop; epilogue reuses [0,17408)
    const int t = threadIdx.x;

    // bijective XCD-chunked swizzle (m204): contiguous wg ranges per XCD
    const int nwg = gridDim.x;
    const int q8 = nwg>>3, r8 = nwg&7;
    const int xcd = blockIdx.x&7, cidx = blockIdx.x>>3;
    const int wg = (xcd<r8 ? xcd*(q8+1) : r8*(q8+1) + (xcd-r8)*q8) + cidx;
    const int mt = wg/NT, ntile = wg - mt*NT;
    const int m0 = mt*128, n0 = ntile*128;

    const int seg = (mode==3)? 0 : n0/768;           // block-uniform
    const float* bias = (mode==3)? b0 : (seg==0?b0: seg==1?b1:b2);
    const int nlb = (mode==3)? n0 : n0 - seg*768;

    const int w = t>>6, lane = t&63, g = lane>>4, c = lane&15;
    const int wm = w>>1, wn = w&1;       // wm 0..3 (32-row band), wn 0..1 (64-col half)

    // staging: thread covers rows {w*8+lrow, 64+w*8+lrow}; dest 16B-slot (lane&7);
    // source chunk (lane&7)^(row&7) so LDS[row][slot] = G[row][slot^(row&7)]
    const int lrow = lane>>3;
    const int lcol = ((lane&7) ^ lrow) * 8;
    const short* pa = A + (size_t)(m0 + w*8 + lrow)*768 + lcol;
    const short* pb = T + (size_t)(n0 + w*8 + lrow)*768 + lcol;

    f32x4 acc[2][4] = {};

    // buffers: buf b -> lA at sh+b*16384, lB at sh+b*16384+8192
    #pragma unroll
    for(int i=0;i<2;i++){
        gload_lds16(pa + (size_t)(i*64)*768, &sh[(i*64 + w*8)*64]);
        gload_lds16(pb + (size_t)(i*64)*768, &sh[8192 + (i*64 + w*8)*64]);
    }
    int bb = 0;
    for(int kk=0; kk<12; kk++){
        if(kk<11){
            short* dstA = &sh[(bb^1)*16384];
            short* dstB = dstA + 8192;
            #pragma unroll
            for(int i=0;i<2;i++){
                gload_lds16(pa + (size_t)(i*64)*768 + (kk+1)*64, &dstA[(i*64 + w*8)*64]);
                gload_lds16(pb + (size_t)(i*64)*768 + (kk+1)*64, &dstB[(i*64 + w*8)*64]);
            }
            asm volatile("s_waitcnt vmcnt(4)" ::: "memory");
        } else {
            asm volatile("s_waitcnt vmcnt(0)" ::: "memory");
        }
        __builtin_amdgcn_s_barrier();
        asm volatile("" ::: "memory");

        const short* LA = &sh[bb*16384];
        const short* LB = LA + 8192;
        short8 af[2][2], bfv[4][2];
        #pragma unroll
        for(int mi=0; mi<2; mi++){
            int row = wm*32 + mi*16 + c;
            int rx = (row&7)<<3;
            af[mi][0] = *(const short8*)&LA[row*64 + ((g*8) ^ rx)];
            af[mi][1] = *(const short8*)&LA[row*64 + ((32 + g*8) ^ rx)];
        }
        #pragma unroll
        for(int ni=0; ni<4; ni++){
            int row = wn*64 + ni*16 + c;
            int rx = (row&7)<<3;
            bfv[ni][0] = *(const short8*)&LB[row*64 + ((g*8) ^ rx)];
            bfv[ni][1] = *(const short8*)&LB[row*64 + ((32 + g*8) ^ rx)];
        }
        __builtin_amdgcn_s_setprio(1);
        #pragma unroll
        for(int mi=0; mi<2; mi++)
            #pragma unroll
            for(int ni=0; ni<4; ni++){
                acc[mi][ni] = __builtin_amdgcn_mfma_f32_16x16x32_bf16(af[mi][0], bfv[ni][0], acc[mi][ni], 0,0,0);
                acc[mi][ni] = __builtin_amdgcn_mfma_f32_16x16x32_bf16(af[mi][1], bfv[ni][1], acc[mi][ni], 0,0,0);
            }
        __builtin_amdgcn_s_setprio(0);
        asm volatile("s_waitcnt lgkmcnt(0)" ::: "memory");
        __builtin_amdgcn_s_barrier();
        asm volatile("" ::: "memory");
        bb ^= 1;
    }

    if(mode==3){
        #pragma unroll
        for(int mi=0; mi<2; mi++) for(int ni=0; ni<4; ni++){
            #pragma unroll
            for(int r=0; r<4; r++){
                int m = m0 + wm*32 + mi*16 + g*4 + r;   // C/D: row=(lane>>4)*4+reg
                int n = n0 + wn*64 + ni*16 + c;         // C/D: col=lane&15
                if(m >= M_) continue;
                of[(size_t)m*768 + n] = acc[mi][ni][r] + bias[n];
            }
        }
        return;
    }

    // mode 0 epilogue: stage bf16 tile to LDS (V-segment transposed), then
    // 16B-coalesced stores. LDS tile [128][LTS] reuses the staging buffer.
    if(seg==2){
        #pragma unroll
        for(int mi=0;mi<2;mi++)
            #pragma unroll
            for(int ni=0;ni<4;ni++){
                int nl_ = wn*64 + ni*16 + c;
                float bv = bias[nlb + nl_];
                s16x4 pk;
                #pragma unroll
                for(int r=0;r<4;r++) pk[r] = (short)f2bf(acc[mi][ni][r] + bv);
                int ml0 = wm*32 + mi*16 + g*4;
                *(s16x4*)&sh[nl_*LTS + ml0] = pk;       // transposed: [n][m]
            }
    } else {
        #pragma unroll
        for(int mi=0;mi<2;mi++)
            #pragma unroll
            for(int ni=0;ni<4;ni++){
                int nl_ = wn*64 + ni*16 + c;
                float bv = bias[nlb + nl_];
                #pragma unroll
                for(int r=0;r<4;r++){
                    int ml = wm*32 + mi*16 + g*4 + r;
                    sh[ml*LTS + nl_] = (short)f2bf(acc[mi][ni][r] + bv);
                }
            }
    }
    __syncthreads();

    #pragma unroll
    for(int i=0;i<4;i++){
        int idx = i*512 + t;
        int rp = idx>>4, ch = idx&15;
        short8 v8 = *(const short8*)&sh[rp*LTS + ch*8];
        if(seg==2){
            // rows rp = local d over 2 heads; cols = m (s)
            int nl = nlb + rp, hh = nl>>6, dd = nl&63;
            int mg = m0 + ch*8;
            if(mg < M_){
                int b0_ = mg/S_, s0 = mg - b0_*S_;
                if(s0+7 < S_ && mg+7 < M_){
                    *(short8*)&ovt[(((size_t)b0_*NH_+hh)*HD_+dd)*SKPAD + s0] = v8;
                } else {
                    for(int j=0;j<8;j++){
                        int m=mg+j;
                        if(m<M_){ int bj=m/S_, sj=m-bj*S_;
                            ovt[(((size_t)bj*NH_+hh)*HD_+dd)*SKPAD+sj]=v8[j]; }
                    }
                }
            }
        } else {
            int m = m0 + rp;
            if(m < M_){
                int b0_ = m/S_, s0 = m - b0_*S_;
                int nl = nlb + ch*8, hh = nl>>6, dd = nl&63;
                if(seg==1) *(short8*)&ok[(((size_t)b0_*NH_+hh)*SKPAD + s0)*HD_ + dd] = v8;
                else       *(short8*)&oq[(((size_t)b0_*NH_+hh)*S_   + s0)*HD_ + dd] = v8;
            }
        }
    }
}

// flash attention: QBLK=128 (each wave owns 32 q-rows = 2 fragments), grid (bh, qtile).
// K/V double-buffered via global_load_lds + counted vmcnt; softmax in exp2 domain;
// row-sum via all-ones MFMA; setprio around MFMA clusters.
__global__ __launch_bounds__(256) void k_attn(
    const short* __restrict__ qh, const short* __restrict__ kh, const short* __restrict__ vt,
    short* __restrict__ ctx)
{
    __shared__ short lK[2][64*64], lV[2][64*64], lP[4*2048];
    const int t = threadIdx.x;
    const int w = t>>6, lane = t&63, g = lane>>4, c = lane&15;
    const int bh = blockIdx.x, b = bh/NH_, h = bh%NH_;
    const int q0 = blockIdx.y*128;

    // per-wave Q staging (32 rows) into own lP region (guarded), then frags to regs
    #pragma unroll
    for(int i=0;i<4;i++){
        int row = i*8 + (lane>>3);
        int e8 = (lane&7)*8;
        int s = q0 + w*32 + row;
        short8 v = {};
        if(s < S_) v = *(const short8*)&qh[((size_t)bh*S_ + s)*HD_ + e8];
        *(short8*)&lP[w*2048 + row*64 + (e8 ^ ((row&7)<<3))] = v;
    }
    short8 qf[2][2];
    #pragma unroll
    for(int qi=0; qi<2; qi++)
        #pragma unroll
        for(int ks=0; ks<2; ks++)
            qf[qi][ks] = *(const short8*)&lP[w*2048 + (qi*16+c)*64 + ((ks*32+g*8) ^ ((c&7)<<3))];

    short8 ones;
    #pragma unroll
    for(int j=0;j<8;j++) ones[j] = (short)0x3F80;    // bf16 1.0

    const int srow = lane>>3;
    const int sw8 = ((lane&7) ^ srow)*8;
    const short* pk0 = kh + ((size_t)bh*SKPAD + w*16 + srow)*64 + sw8;
    const short* pv0 = vt + ((size_t)bh*64 + w*16 + srow)*SKPAD + sw8;

    // prologue: stage tile 0 into buffer 0
    #pragma unroll
    for(int i=0;i<2;i++){
        gload_lds16(pk0 + i*8*64,    &lK[0][(w*16+i*8)*64]);
        gload_lds16(pv0 + i*8*SKPAD, &lV[0][(w*16+i*8)*64]);
    }

    float m_run[2][4], l_run[2][4];
    f32x4 O[2][4] = {};
    #pragma unroll
    for(int qi=0;qi<2;qi++)
        #pragma unroll
        for(int r=0;r<4;r++){ m_run[qi][r] = -3e38f; l_run[qi][r] = 0.f; }

    int bb = 0;
    for(int kt=0; kt<10; kt++){
        if(kt<9){
            const short* pk = pk0 + (kt+1)*4096;   // 64 rows * 64
            const short* pv = pv0 + (kt+1)*64;     // 64 cols
            #pragma unroll
            for(int i=0;i<2;i++){
                gload_lds16(pk + i*8*64,    &lK[bb^1][(w*16+i*8)*64]);
                gload_lds16(pv + i*8*SKPAD, &lV[bb^1][(w*16+i*8)*64]);
            }
            asm volatile("s_waitcnt vmcnt(4)" ::: "memory");
        } else {
            asm volatile("s_waitcnt vmcnt(0)" ::: "memory");
        }
        __builtin_amdgcn_s_barrier();
        asm volatile("" ::: "memory");

        const short* LK = lK[bb]; const short* LV = lV[bb];

        // S = Q K^T (per wave: 2 x 16 q-rows x 64 keys), scaled into log2 domain
        float sv[2][4][4];
        #pragma unroll
        for(int nt=0; nt<4; nt++){
            int row = nt*16 + c;
            int rx = (row&7)<<3;
            short8 kf[2];
            kf[0] = *(const short8*)&LK[row*64 + ((g*8) ^ rx)];
            kf[1] = *(const short8*)&LK[row*64 + ((32+g*8) ^ rx)];
            __builtin_amdgcn_s_setprio(1);
            #pragma unroll
            for(int qi=0; qi<2; qi++){
                f32x4 sa = {};
                sa = __builtin_amdgcn_mfma_f32_16x16x32_bf16(qf[qi][0], kf[0], sa, 0,0,0);
                sa = __builtin_amdgcn_mfma_f32_16x16x32_bf16(qf[qi][1], kf[1], sa, 0,0,0);
                #pragma unroll
                for(int r=0;r<4;r++) sv[qi][nt][r] = sa[r]*0.18033688011f;  // /8 * log2(e)
            }
            __builtin_amdgcn_s_setprio(0);
        }
        if(kt==9){
            #pragma unroll
            for(int nt=0; nt<4; nt++){
                int key = 576 + nt*16 + c;
                if(key >= S_){
                    #pragma unroll
                    for(int qi=0;qi<2;qi++)
                        #pragma unroll
                        for(int r=0;r<4;r++) sv[qi][nt][r] = -3e38f;
                }
            }
        }
        // online softmax: max via shuffles (rows on 16 c-lanes), sum via ones-MFMA
        float fac[2][4];
        #pragma unroll
        for(int qi=0; qi<2; qi++)
            #pragma unroll
            for(int r=0;r<4;r++){
                float mx = fmaxf(fmaxf(sv[qi][0][r],sv[qi][1][r]),fmaxf(sv[qi][2][r],sv[qi][3][r]));
                for(int off=1; off<16; off<<=1) mx = fmaxf(mx, __shfl_xor(mx, off));
                float nm = fmaxf(m_run[qi][r], mx);
                fac[qi][r] = __builtin_amdgcn_exp2f(m_run[qi][r] - nm);
                m_run[qi][r] = nm;
            }
        #pragma unroll
        for(int qi=0; qi<2; qi++)
            #pragma unroll
            for(int nt=0; nt<4; nt++)
                #pragma unroll
                for(int r=0;r<4;r++){
                    float p = __builtin_amdgcn_exp2f(sv[qi][nt][r] - m_run[qi][r]);
                    int prow = g*4 + r;
                    lP[w*2048 + qi*1024 + prow*64 + ((nt*16 + c) ^ ((prow&7)<<3))] = (short)f2bf(p);
                }
        // P fragments (own-wave LDS region)
        short8 pf[2][2];
        #pragma unroll
        for(int qi=0; qi<2; qi++)
            #pragma unroll
            for(int ks=0; ks<2; ks++)
                pf[qi][ks] = *(const short8*)&lP[w*2048 + qi*1024 + c*64 + ((ks*32+g*8) ^ ((c&7)<<3))];
        // row-sum = P . 1  (output row = g*4+r matches l_run indexing)
        __builtin_amdgcn_s_setprio(1);
        #pragma unroll
        for(int qi=0; qi<2; qi++){
            f32x4 rs = {};
            rs = __builtin_amdgcn_mfma_f32_16x16x32_bf16(pf[qi][0], ones, rs, 0,0,0);
            rs = __builtin_amdgcn_mfma_f32_16x16x32_bf16(pf[qi][1], ones, rs, 0,0,0);
            #pragma unroll
            for(int r=0;r<4;r++) l_run[qi][r] = l_run[qi][r]*fac[qi][r] + rs[r];
        }
        __builtin_amdgcn_s_setprio(0);
        #pragma unroll
        for(int qi=0; qi<2; qi++)
            #pragma unroll
            for(int nt=0;nt<4;nt++)
                #pragma unroll
                for(int r=0;r<4;r++) O[qi][nt][r] *= fac[qi][r];

        // O += P V  (V^T tile rows = d; vf reused across both q-frags)
        __builtin_amdgcn_s_setprio(1);
        #pragma unroll
        for(int nt=0; nt<4; nt++){
            int vrow = nt*16 + c;
            int rx = (vrow&7)<<3;
            short8 vf[2];
            vf[0] = *(const short8*)&LV[vrow*64 + ((g*8) ^ rx)];
            vf[1] = *(const short8*)&LV[vrow*64 + ((32+g*8) ^ rx)];
            #pragma unroll
            for(int qi=0; qi<2; qi++){
                O[qi][nt] = __builtin_amdgcn_mfma_f32_16x16x32_bf16(pf[qi][0], vf[0], O[qi][nt], 0,0,0);
                O[qi][nt] = __builtin_amdgcn_mfma_f32_16x16x32_bf16(pf[qi][1], vf[1], O[qi][nt], 0,0,0);
            }
        }
        __builtin_amdgcn_s_setprio(0);
        asm volatile("s_waitcnt lgkmcnt(0)" ::: "memory");
        __builtin_amdgcn_s_barrier();
        asm volatile("" ::: "memory");
        bb ^= 1;
    }

    #pragma unroll
    for(int qi=0; qi<2; qi++)
        #pragma unroll
        for(int nt=0; nt<4; nt++)
            #pragma unroll
            for(int r=0;r<4;r++){
                int s = q0 + w*32 + qi*16 + g*4 + r;
                if(s < S_){
                    float val = O[qi][nt][r] / l_run[qi][r];
                    ctx[((size_t)b*S_ + s)*H_ + h*HD_ + nt*16 + c] = (short)f2bf(val);
                }
            }
}

extern "C" void kernel_launch(void* const* d_in, const int* in_sizes, int n_in,
                              void* d_out, int out_size, void* d_ws, size_t ws_size,
                              hipStream_t stream)
{
    const float* hs = (const float*)d_in[0];
    const float* Wq = (const float*)d_in[1];
    const float* bq = (const float*)d_in[2];
    const float* Wk = (const float*)d_in[3];
    const float* bk = (const float*)d_in[4];
    const float* Wv = (const float*)d_in[5];
    const float* bv = (const float*)d_in[6];
    const float* Wo = (const float*)d_in[7];
    const float* bo = (const float*)d_in[8];
    float* out = (float*)d_out;

    char* ws = (char*)d_ws;
    // abf/ctx: 4736*768*2 = 7,274,496
    // Wt x4:   768*768*2  = 1,179,648 each, contiguous -> fused [2304][768] at wqt
    // qh: 96*577*64*2 = 7,090,176 ; kh: 96*640*64*2 = 7,864,320 ; vt: 96*64*640*2 = 7,864,320
    short* abf = (short*)(ws);
    short* ctx = abf;                               // reuse after QKV GEMM
    short* wqt = (short*)(ws + 7274496);
    short* wkt = (short*)(ws + 7274496 + 1179648);
    short* wvt = (short*)(ws + 7274496 + 2*1179648);
    short* wot = (short*)(ws + 7274496 + 3*1179648);
    short* qh  = (short*)(ws + 11993088);
    short* kh  = (short*)(ws + 19083264);
    short* vt  = (short*)(ws + 26947584);
    // total: 34,811,904 B

    k_prep<<<2733, 256, 0, stream>>>(hs, abf, Wq,Wk,Wv,Wo, wqt,wkt,wvt,wot, kh, vt);
    k_gemm<<<666, 512, 0, stream>>>(abf, wqt, bq,bk,bv, qh,kh,vt, nullptr, 0, 18);
    k_attn<<<dim3(96,5), 256, 0, stream>>>(qh, kh, vt, ctx);
    k_gemm<<<222, 512, 0, stream>>>(ctx, wot, bo,bo,bo, nullptr,nullptr,nullptr, out, 3, 6);
}